// Round 8
// baseline (336.762 us; speedup 1.0000x reference)
//
#include <hip/hip_runtime.h>

#define D_MODEL 1024
#define D_STATE 16
#define D_CONV  4
#define D_INNER 2048
#define DT_RANK 64
#define BATCH   2
#define SEQLEN  2048
#define NTOK    (BATCH * SEQLEN)   // 4096
#define NCH     64                 // scan chunks
#define LC      (SEQLEN / NCH)     // 32 steps per chunk
#define XKS     8                  // x_proj split-K factor
#define XNC     96                 // dt_rank + 2*d_state

// FACTS (r2-r12): inputs f32; d_out read as f32; bf16 internal copies for MFMA;
// async global_load_lds verified (r9); out_proj split-K regressed (r10); ws peak
// <= 187,171,328 B (r11 abort); dt_proj MFMA verified (r12). r13: out_proj BN=64
// + M-major. r14: in_proj 256^2/BK=64 8-phase — win. r15: scan power-chain —
// win. r16: conv 4x4 blocks — win. r17: out_proj 2-phase counted pipeline — win.
// r18 REGRESSED (conv fused into gemm1: spill traffic + barrier skew; reverted).
// r19: revert + gemm_dt single-stage + gate __expf — win (316.8, best).
// r20: scan n-split — lane l owns (d = l&31 within 32-group, nh = l>>5 -> 8
// states); serial chain halves, blocks 1024->2048. Power-chain trees reproduced
// op-for-op per half (h/S bit-identical); apply's y via per-half tree +
// __shfl_xor(32). mfma_probe folded into cvt_all block 0 (11 -> 10 dispatches).
// r21: r20 RESUBMIT — round 7 bench was an infra container failure (no kernel
// verdict); code audit found no defect (uniform-branch probe, disjoint S
// writes, unconditional shfl, aligned ld8f).

// ---------- bf16 helpers ----------
__device__ __forceinline__ float bf2f(unsigned short v) {
    union { unsigned int u; float f; } c; c.u = ((unsigned int)v) << 16; return c.f;
}
__device__ __forceinline__ unsigned short f2bf(float f) {
    union { unsigned int u; float f; } c; c.f = f;
    unsigned int r = c.u + 0x7FFF + ((c.u >> 16) & 1);   // RNE
    return (unsigned short)(r >> 16);
}

__device__ __forceinline__ int sniff_bf(const void* Dp) {
    return (((const unsigned int*)Dp)[0] == 0x3F803F80u) ? 1 : 0;
}

__device__ __forceinline__ float ldF(const void* p, size_t idx, int isbf) {
    return isbf ? bf2f(((const unsigned short*)p)[idx]) : ((const float*)p)[idx];
}
__device__ __forceinline__ void ld8f(const float* p, float* o) {
#pragma unroll
    for (int q = 0; q < 2; q++) {
        float4 v = *(const float4*)(p + 4 * q);
        o[4 * q + 0] = v.x; o[4 * q + 1] = v.y; o[4 * q + 2] = v.z; o[4 * q + 3] = v.w;
    }
}

typedef __attribute__((ext_vector_type(8))) __bf16 bf16x8;
typedef __attribute__((ext_vector_type(4))) float  f32x4;

// ---------------------------------------------------------------------------
// MFMA layout probe (r8-verified), now a block-0 section of cvt_all.
// dmap[lane*4+r] = row | col<<4 in loader coords.
// ---------------------------------------------------------------------------
__device__ void probe_dmap_block(int t, int* __restrict__ dmap)
{
    __shared__ alignas(16) unsigned short PAs[16 * 32];
    __shared__ alignas(16) unsigned short PBs[16 * 32];
    const int q = (t & 63) >> 4, l15 = t & 15;

    if (t < 64)
        for (int idx = t; idx < 512; idx += 64) {
            PAs[idx] = f2bf((float)(idx >> 5));
            PBs[idx] = f2bf(0.03125f);
        }
    __syncthreads();
    f32x4 acc1 = {0.f, 0.f, 0.f, 0.f};
    if (t < 64) {
        bf16x8 a1 = *(const bf16x8*)&PAs[l15 * 32 + q * 8];
        bf16x8 b1 = *(const bf16x8*)&PBs[l15 * 32 + q * 8];
        acc1 = __builtin_amdgcn_mfma_f32_16x16x32_bf16(a1, b1, acc1, 0, 0, 0);
    }
    __syncthreads();
    if (t < 64)
        for (int idx = t; idx < 512; idx += 64) {
            PAs[idx] = f2bf(0.03125f);
            PBs[idx] = f2bf((float)(idx >> 5));
        }
    __syncthreads();
    if (t < 64) {
        bf16x8 a2 = *(const bf16x8*)&PAs[l15 * 32 + q * 8];
        bf16x8 b2 = *(const bf16x8*)&PBs[l15 * 32 + q * 8];
        f32x4 acc2 = {0.f, 0.f, 0.f, 0.f};
        acc2 = __builtin_amdgcn_mfma_f32_16x16x32_bf16(a2, b2, acc2, 0, 0, 0);
#pragma unroll
        for (int r = 0; r < 4; r++) {
            int ma = (int)(acc1[r] + 0.5f);
            int nb = (int)(acc2[r] + 0.5f);
            if (ma < 0 || ma > 15 || nb < 0 || nb > 15) { ma = q * 4 + r; nb = l15; }
            dmap[t * 4 + r] = ma | (nb << 4);
        }
    }
}

// ---------------------------------------------------------------------------
// Fused bf16 conversion for the 4 MFMA operand copies (8 elems/thread)
// + block-0 MFMA layout probe.
// ---------------------------------------------------------------------------
#define CVT_N0 (NTOK * D_MODEL)        // hidden   4,194,304
#define CVT_N1 (2 * D_INNER * D_MODEL) // in_proj  4,194,304
#define CVT_N2 (D_MODEL * D_INNER)     // out_proj 2,097,152
#define CVT_N3 (D_INNER * DT_RANK)     // dt_proj    131,072
#define CVT_TOT (CVT_N0 + CVT_N1 + CVT_N2 + CVT_N3)

__device__ __forceinline__ void cvt8(const void* in, unsigned short* out,
                                     size_t e0, int isbf)
{
    if (isbf) {
        *(uint4*)(out + e0) = *(const uint4*)((const unsigned short*)in + e0);
    } else {
        const float* f = (const float*)in + e0;
        float4 a = *(const float4*)f;
        float4 b = *(const float4*)(f + 4);
        ushort4 o0 = { f2bf(a.x), f2bf(a.y), f2bf(a.z), f2bf(a.w) };
        ushort4 o1 = { f2bf(b.x), f2bf(b.y), f2bf(b.z), f2bf(b.w) };
        *(ushort4*)(out + e0)     = o0;
        *(ushort4*)(out + e0 + 4) = o1;
    }
}

__launch_bounds__(256)
__global__ void cvt_all(const void* __restrict__ hid, const void* __restrict__ ipw,
                        const void* __restrict__ opw, const void* __restrict__ dtw,
                        unsigned short* __restrict__ hidB, unsigned short* __restrict__ ipwB,
                        unsigned short* __restrict__ opwB, unsigned short* __restrict__ dtwB,
                        const void* __restrict__ Dp, int* __restrict__ dmap)
{
    if (blockIdx.x == 0) probe_dmap_block(threadIdx.x, dmap);

    const int isbf = sniff_bf(Dp);
    size_t e = ((size_t)blockIdx.x * 256 + threadIdx.x) * 8;
    if (e < CVT_N0) { cvt8(hid, hidB, e, isbf); return; }
    e -= CVT_N0;
    if (e < CVT_N1) { cvt8(ipw, ipwB, e, isbf); return; }
    e -= CVT_N1;
    if (e < CVT_N2) { cvt8(opw, opwB, e, isbf); return; }
    e -= CVT_N2;
    if (e < CVT_N3) { cvt8(dtw, dtwB, e, isbf); }
}

// ---------------------------------------------------------------------------
__device__ __forceinline__ void gl2lds16(const void* g, void* l) {
    __builtin_amdgcn_global_load_lds(
        (const __attribute__((address_space(1))) unsigned int*)g,
        (__attribute__((address_space(3))) unsigned int*)l,
        16, 0, 0);
}

// ===========================================================================
// in_proj GEMM: 256x256 tile, BK=64, 8 waves, 8-phase schedule (r14-verified).
// ===========================================================================
__device__ __forceinline__ void stage_half(const unsigned short* __restrict__ G,
                                           int grow0, int K, int k0,
                                           unsigned short* ldsAB, int half, int t)
{
    const int r8  = t >> 3;                 // 0..63: row within 64-row group
    const int c8  = t & 7;                  // physical 16B slot
    const int swz = (c8 ^ (r8 & 7)) << 3;   // logical col in shorts
#pragma unroll
    for (int j = 0; j < 2; j++) {
        const int row = half * 128 + j * 64 + r8;
        gl2lds16(&G[(size_t)(grow0 + row) * K + k0 + swz],
                 &ldsAB[row * 64 + c8 * 8]);
    }
}

__device__ __forceinline__ bf16x8 ldsfrag(const unsigned short* p, int row, int slot) {
    return *(const bf16x8*)&p[row * 64 + ((slot ^ (row & 7)) << 3)];
}

__launch_bounds__(512)
__global__ void gemm1_8ph(const unsigned short* __restrict__ A,
                          const unsigned short* __restrict__ B,
                          float* __restrict__ C,
                          int M, int N, int K,
                          const int* __restrict__ dmap)
{
    extern __shared__ __align__(16) unsigned short lds[];
    unsigned short* A0l = lds;              // buf0 A [256][64]
    unsigned short* B0l = lds + 16384;      // buf0 B
    unsigned short* A1l = lds + 32768;      // buf1 A
    unsigned short* B1l = lds + 49152;      // buf1 B

    const int t    = threadIdx.x;
    const int lane = t & 63;
    const int w    = t >> 6;
    const int wm   = (w >> 2) * 128, wn = (w & 3) * 64;
    const int q    = lane >> 4, l15 = lane & 15;

    const int nbn  = N >> 8;
    const int nwg  = (M >> 8) * nbn;        // 256 here: % 8 == 0 -> bijective
    const int orig = blockIdx.x;
    const int wg   = (orig & 7) * (nwg >> 3) + (orig >> 3);
    const int bm   = wg / nbn, bn = wg % nbn;
    const int m0   = bm << 8, n0 = bn << 8;
    const int NT   = K >> 6;

    int mp[4];
#pragma unroll
    for (int r = 0; r < 4; r++) mp[r] = dmap[lane * 4 + r];

    f32x4 acc[8][4];
#pragma unroll
    for (int i = 0; i < 8; i++)
#pragma unroll
        for (int j = 0; j < 4; j++) acc[i][j] = (f32x4){0.f, 0.f, 0.f, 0.f};

    // ---- prologue: tile0 {B,A}, tile1 {B}; wait oldest 8 (= tile0 complete)
    stage_half(B, n0, K, 0, B0l, 0, t);
    stage_half(B, n0, K, 0, B0l, 1, t);
    stage_half(A, m0, K, 0, A0l, 0, t);
    stage_half(A, m0, K, 0, A0l, 1, t);
    {
        const int k1 = (NT > 1 ? 64 : 0);
        stage_half(B, n0, K, k1, B1l, 0, t);
        stage_half(B, n0, K, k1, B1l, 1, t);
    }
    asm volatile("s_waitcnt vmcnt(4)" ::: "memory");
    __builtin_amdgcn_s_barrier();

#pragma unroll 2
    for (int tt = 0; tt < NT; ++tt) {
        const int p = tt & 1;
        const unsigned short* Ac = p ? A1l : A0l;
        const unsigned short* Bc = p ? B1l : B0l;
        unsigned short* Anx = p ? A0l : A1l;   // tile tt+1 A (other buf)
        unsigned short* Bnx = p ? B1l : B0l;   // tile tt+2 B (same buf, dead after ph1)
        const int kA = (tt + 1 < NT ? tt + 1 : 0) << 6;
        const int kB = (tt + 2 < NT ? tt + 2 : 0) << 6;

        bf16x8 af[4][2], b0r[2][2], b1r[2][2];

        // ---------------- phase 0: quadrant (mh0, nh0)
#pragma unroll
        for (int i = 0; i < 4; i++)
#pragma unroll
            for (int ks = 0; ks < 2; ks++)
                af[i][ks] = ldsfrag(Ac, wm + i * 16 + l15, ks * 4 + q);
#pragma unroll
        for (int j = 0; j < 2; j++)
#pragma unroll
            for (int ks = 0; ks < 2; ks++)
                b0r[j][ks] = ldsfrag(Bc, wn + j * 16 + l15, ks * 4 + q);
        stage_half(A, m0, K, kA, Anx, 0, t);
        asm volatile("" ::: "memory");
        __builtin_amdgcn_s_barrier();
        __builtin_amdgcn_s_setprio(1);
#pragma unroll
        for (int i = 0; i < 4; i++)
#pragma unroll
            for (int j = 0; j < 2; j++)
#pragma unroll
                for (int ks = 0; ks < 2; ks++)
                    acc[i][j] = __builtin_amdgcn_mfma_f32_16x16x32_bf16(
                        af[i][ks], b0r[j][ks], acc[i][j], 0, 0, 0);
        __builtin_amdgcn_s_setprio(0);
        asm volatile("" ::: "memory");
        __builtin_amdgcn_s_barrier();

        // ---------------- phase 1: quadrant (mh0, nh1)
#pragma unroll
        for (int j = 0; j < 2; j++)
#pragma unroll
            for (int ks = 0; ks < 2; ks++)
                b1r[j][ks] = ldsfrag(Bc, wn + 32 + j * 16 + l15, ks * 4 + q);
        stage_half(A, m0, K, kA, Anx, 1, t);
        asm volatile("" ::: "memory");
        __builtin_amdgcn_s_barrier();
        __builtin_amdgcn_s_setprio(1);
#pragma unroll
        for (int i = 0; i < 4; i++)
#pragma unroll
            for (int j = 0; j < 2; j++)
#pragma unroll
                for (int ks = 0; ks < 2; ks++)
                    acc[i][2 + j] = __builtin_amdgcn_mfma_f32_16x16x32_bf16(
                        af[i][ks], b1r[j][ks], acc[i][2 + j], 0, 0, 0);
        __builtin_amdgcn_s_setprio(0);
        asm volatile("" ::: "memory");
        __builtin_amdgcn_s_barrier();

        // ---------------- phase 2: quadrant (mh1, nh1)
#pragma unroll
        for (int i = 0; i < 4; i++)
#pragma unroll
            for (int ks = 0; ks < 2; ks++)
                af[i][ks] = ldsfrag(Ac, wm + 64 + i * 16 + l15, ks * 4 + q);
        stage_half(B, n0, K, kB, Bnx, 0, t);
        asm volatile("" ::: "memory");
        __builtin_amdgcn_s_barrier();
        __builtin_amdgcn_s_setprio(1);
#pragma unroll
        for (int i = 0; i < 4; i++)
#pragma unroll
            for (int j = 0; j < 2; j++)
#pragma unroll
                for (int ks = 0; ks < 2; ks++)
                    acc[4 + i][2 + j] = __builtin_amdgcn_mfma_f32_16x16x32_bf16(
                        af[i][ks], b1r[j][ks], acc[4 + i][2 + j], 0, 0, 0);
        __builtin_amdgcn_s_setprio(0);
        asm volatile("" ::: "memory");
        __builtin_amdgcn_s_barrier();

        // ---------------- phase 3: quadrant (mh1, nh0)
        stage_half(B, n0, K, kB, Bnx, 1, t);
        asm volatile("" ::: "memory");
        __builtin_amdgcn_s_barrier();
        __builtin_amdgcn_s_setprio(1);
#pragma unroll
        for (int i = 0; i < 4; i++)
#pragma unroll
            for (int j = 0; j < 2; j++)
#pragma unroll
                for (int ks = 0; ks < 2; ks++)
                    acc[4 + i][j] = __builtin_amdgcn_mfma_f32_16x16x32_bf16(
                        af[i][ks], b0r[j][ks], acc[4 + i][j], 0, 0, 0);
        __builtin_amdgcn_s_setprio(0);
        asm volatile("s_waitcnt vmcnt(4)" ::: "memory");
        __builtin_amdgcn_s_barrier();
    }

    // ---- epilogue
#pragma unroll
    for (int i = 0; i < 8; i++) {
#pragma unroll
        for (int r = 0; r < 4; r++) {
            const int mo = mp[r] & 15, no = mp[r] >> 4;
            const int m = m0 + wm + i * 16 + mo;
#pragma unroll
            for (int j = 0; j < 4; j++) {
                const int n = n0 + wn + j * 16 + no;
                C[(size_t)m * N + n] = acc[i][j][r];
            }
        }
    }
}

// ===========================================================================
// out_proj GEMM: 128x64 tile, BK=64, 4 waves, 2-phase counted pipeline
// (r17-verified). T2 XOR-swizzle. Grid 512 = 2 blocks/CU.
// ===========================================================================
__device__ __forceinline__ void stage_op(const unsigned short* __restrict__ A,
                                         const unsigned short* __restrict__ B,
                                         int m0, int n0, int K, int k0,
                                         unsigned short* Al, unsigned short* Bl, int t)
{
    const int r   = t >> 3;                 // 0..31
    const int c8  = t & 7;                  // physical 16B slot
    const int swz = (c8 ^ (r & 7)) << 3;    // logical col in shorts
#pragma unroll
    for (int j = 0; j < 4; j++) {           // A rows 0..127
        const int row = j * 32 + r;
        gl2lds16(&A[(size_t)(m0 + row) * K + k0 + swz], &Al[row * 64 + c8 * 8]);
    }
#pragma unroll
    for (int j = 0; j < 2; j++) {           // B rows 0..63
        const int row = j * 32 + r;
        gl2lds16(&B[(size_t)(n0 + row) * K + k0 + swz], &Bl[row * 64 + c8 * 8]);
    }
}

__launch_bounds__(256)
__global__ void gemm_op_2ph(const unsigned short* __restrict__ A,   // yg [4096][2048]
                            const unsigned short* __restrict__ B,   // opwB [1024][2048]
                            float* __restrict__ C,                  // [4096][1024]
                            const int* __restrict__ dmap)
{
    constexpr int M = NTOK, N = D_MODEL, K = D_INNER;
    constexpr int NT = K / 64;               // 32
    __shared__ alignas(16) unsigned short Al[2][128 * 64];  // 32 KB
    __shared__ alignas(16) unsigned short Bl[2][64 * 64];   // 16 KB

    const int t    = threadIdx.x;
    const int lane = t & 63;
    const int w    = t >> 6;
    const int wm   = (w >> 1) * 64, wn = (w & 1) * 32;
    const int q    = lane >> 4, l15 = lane & 15;

    const int nbn  = N / 64;                 // 16
    const int nwg  = (M / 128) * nbn;        // 512, % 8 == 0
    const int orig = blockIdx.x;
    const int wg   = (orig & 7) * (nwg >> 3) + (orig >> 3);
    const int bm   = wg / nbn, bn = wg % nbn;
    const int m0   = bm * 128, n0 = bn * 64;

    int mp[4];
#pragma unroll
    for (int r = 0; r < 4; r++) mp[r] = dmap[lane * 4 + r];

    f32x4 acc[4][2];
#pragma unroll
    for (int i = 0; i < 4; i++)
#pragma unroll
        for (int j = 0; j < 2; j++) acc[i][j] = (f32x4){0.f, 0.f, 0.f, 0.f};

    stage_op(A, B, m0, n0, K, 0, Al[0], Bl[0], t);
    asm volatile("s_waitcnt vmcnt(0)" ::: "memory");
    __builtin_amdgcn_s_barrier();

#pragma unroll 2
    for (int tt = 0; tt < NT - 1; ++tt) {
        const int cur = tt & 1;
        stage_op(A, B, m0, n0, K, (tt + 1) * 64, Al[cur ^ 1], Bl[cur ^ 1], t);

        bf16x8 af[4][2], bfr[2][2];
#pragma unroll
        for (int i = 0; i < 4; i++)
#pragma unroll
            for (int ks = 0; ks < 2; ks++)
                af[i][ks] = ldsfrag(Al[cur], wm + i * 16 + l15, ks * 4 + q);
#pragma unroll
        for (int j = 0; j < 2; j++)
#pragma unroll
            for (int ks = 0; ks < 2; ks++)
                bfr[j][ks] = ldsfrag(Bl[cur], wn + j * 16 + l15, ks * 4 + q);
        __builtin_amdgcn_s_setprio(1);
#pragma unroll
        for (int i = 0; i < 4; i++)
#pragma unroll
            for (int j = 0; j < 2; j++)
#pragma unroll
                for (int ks = 0; ks < 2; ks++)
                    acc[i][j] = __builtin_amdgcn_mfma_f32_16x16x32_bf16(
                        af[i][ks], bfr[j][ks], acc[i][j], 0, 0, 0);
        __builtin_amdgcn_s_setprio(0);
        asm volatile("s_waitcnt vmcnt(0)" ::: "memory");
        __builtin_amdgcn_s_barrier();
    }

    {
        const int cur = (NT - 1) & 1;
        bf16x8 af[4][2], bfr[2][2];
#pragma unroll
        for (int i = 0; i < 4; i++)
#pragma unroll
            for (int ks = 0; ks < 2; ks++)
                af[i][ks] = ldsfrag(Al[cur], wm + i * 16 + l15, ks * 4 + q);
#pragma unroll
        for (int j = 0; j < 2; j++)
#pragma unroll
            for (int ks = 0; ks < 2; ks++)
                bfr[j][ks] = ldsfrag(Bl[cur], wn + j * 16 + l15, ks * 4 + q);
#pragma unroll
        for (int i = 0; i < 4; i++)
#pragma unroll
            for (int j = 0; j < 2; j++)
#pragma unroll
                for (int ks = 0; ks < 2; ks++)
                    acc[i][j] = __builtin_amdgcn_mfma_f32_16x16x32_bf16(
                        af[i][ks], bfr[j][ks], acc[i][j], 0, 0, 0);
    }

#pragma unroll
    for (int i = 0; i < 4; i++) {
#pragma unroll
        for (int r = 0; r < 4; r++) {
            const int mo = mp[r] & 15, no = mp[r] >> 4;
            const int m = m0 + wm + i * 16 + mo;
#pragma unroll
            for (int j = 0; j < 2; j++) {
                const int n = n0 + wn + j * 16 + no;
                C[(size_t)m * N + n] = acc[i][j][r];
            }
        }
    }
}

// ===========================================================================
// dt_proj GEMM (K=64): 128x128 tile, single 32KB stage (r19-verified).
// ===========================================================================
__launch_bounds__(256)
__global__ void gemm_dt(const unsigned short* __restrict__ A,   // xdt [4096][64]
                        const unsigned short* __restrict__ B,   // dtwB [2048][64]
                        float* __restrict__ C,                  // dlt [4096][2048]
                        const int* __restrict__ dmap,
                        const void* __restrict__ bias,
                        const void* __restrict__ Dp)
{
    constexpr int M = NTOK, N = D_INNER, K = DT_RANK;   // 4096, 2048, 64
    __shared__ alignas(16) unsigned short Al[128 * 64]; // 16 KB
    __shared__ alignas(16) unsigned short Bl[128 * 64]; // 16 KB

    const int t    = threadIdx.x;
    const int lane = t & 63;
    const int w    = t >> 6;
    const int wm   = (w >> 1) * 64, wn = (w & 1) * 64;
    const int q    = lane >> 4, l15 = lane & 15;

    const int nbn  = N / 128;                // 16
    const int nwg  = (M / 128) * nbn;        // 512, % 8 == 0 -> bijective
    const int orig = blockIdx.x;
    const int wg   = (orig & 7) * (nwg >> 3) + (orig >> 3);
    const int bm   = wg / nbn, bn = wg % nbn;
    const int m0   = bm * 128, n0 = bn * 128;

    int mp[4];
#pragma unroll
    for (int r = 0; r < 4; r++) mp[r] = dmap[lane * 4 + r];

    {
        const int r   = t >> 3;              // 0..31
        const int c8  = t & 7;
        const int swz = (c8 ^ (r & 7)) << 3;
#pragma unroll
        for (int j = 0; j < 4; j++) {
            const int row = j * 32 + r;
            gl2lds16(&A[(size_t)(m0 + row) * K + swz], &Al[row * 64 + c8 * 8]);
            gl2lds16(&B[(size_t)(n0 + row) * K + swz], &Bl[row * 64 + c8 * 8]);
        }
    }
    asm volatile("s_waitcnt vmcnt(0)" ::: "memory");
    __builtin_amdgcn_s_barrier();

    f32x4 acc[4][4];
#pragma unroll
    for (int i = 0; i < 4; i++)
#pragma unroll
        for (int j = 0; j < 4; j++) acc[i][j] = (f32x4){0.f, 0.f, 0.f, 0.f};

    bf16x8 af[4][2], bfr[4][2];
#pragma unroll
    for (int i = 0; i < 4; i++)
#pragma unroll
        for (int ks = 0; ks < 2; ks++)
            af[i][ks] = ldsfrag(Al, wm + i * 16 + l15, ks * 4 + q);
#pragma unroll
    for (int j = 0; j < 4; j++)
#pragma unroll
        for (int ks = 0; ks < 2; ks++)
            bfr[j][ks] = ldsfrag(Bl, wn + j * 16 + l15, ks * 4 + q);
#pragma unroll
    for (int i = 0; i < 4; i++)
#pragma unroll
        for (int j = 0; j < 4; j++)
#pragma unroll
            for (int ks = 0; ks < 2; ks++)
                acc[i][j] = __builtin_amdgcn_mfma_f32_16x16x32_bf16(
                    af[i][ks], bfr[j][ks], acc[i][j], 0, 0, 0);

    const int isbf = sniff_bf(Dp);
#pragma unroll
    for (int i = 0; i < 4; i++) {
#pragma unroll
        for (int r = 0; r < 4; r++) {
            const int mo = mp[r] & 15, no = mp[r] >> 4;
            const int m = m0 + wm + i * 16 + mo;
#pragma unroll
            for (int j = 0; j < 4; j++) {
                const int n = n0 + wn + j * 16 + no;
                float v = acc[i][j][r] + ldF(bias, n, isbf);
                v = fmaxf(v, 0.f) + __logf(1.f + __expf(-fabsf(v)));   // softplus
                C[(size_t)m * N + n] = v;
            }
        }
    }
}

// ---------------------------------------------------------------------------
// x_proj split-K: part[z][M][96] = xl[:, zKc:(z+1)Kc] @ x_proj_w[:, zKc:]^T
// ---------------------------------------------------------------------------
__launch_bounds__(256)
__global__ void xproj_splitk(const float* __restrict__ A,   // xl [4096,2048]
                             const float* __restrict__ B,   // x_proj_w [96,2048]
                             float* __restrict__ part)      // [XKS,4096,96]
{
    __shared__ alignas(16) float As[16][68];
    __shared__ alignas(16) float Bs[16][68];
    const int t  = threadIdx.x;
    const int m0 = blockIdx.y * 64, n0 = blockIdx.x * 64;
    const int koff = blockIdx.z * (D_INNER / XKS);           // 256-wide K chunk
    const int lr = t >> 2;
    const int lk = (t & 3) * 4;
    const int tm = t >> 4, tn = t & 15;

    float acc[4][4];
#pragma unroll
    for (int i = 0; i < 4; i++)
#pragma unroll
        for (int j = 0; j < 4; j++) acc[i][j] = 0.f;

    for (int k0 = koff; k0 < koff + D_INNER / XKS; k0 += 16) {
        float av[4], bv[4];
        {
            const int m = m0 + lr;
            float4 p = *(const float4*)&A[(size_t)m * D_INNER + k0 + lk];
            av[0] = p.x; av[1] = p.y; av[2] = p.z; av[3] = p.w;
        }
        {
            const int n = n0 + lr;
            if (n < XNC) {
                float4 p = *(const float4*)&B[(size_t)n * D_INNER + k0 + lk];
                bv[0] = p.x; bv[1] = p.y; bv[2] = p.z; bv[3] = p.w;
            } else { bv[0] = bv[1] = bv[2] = bv[3] = 0.f; }
        }
        __syncthreads();
#pragma unroll
        for (int i = 0; i < 4; i++) { As[lk + i][lr] = av[i]; Bs[lk + i][lr] = bv[i]; }
        __syncthreads();

#pragma unroll
        for (int kk = 0; kk < 16; kk++) {
            float4 a = *(const float4*)&As[kk][tm * 4];
            float4 b = *(const float4*)&Bs[kk][tn * 4];
            float aa[4] = { a.x, a.y, a.z, a.w };
            float bb[4] = { b.x, b.y, b.z, b.w };
#pragma unroll
            for (int i = 0; i < 4; i++)
#pragma unroll
                for (int j = 0; j < 4; j++) acc[i][j] = fmaf(aa[i], bb[j], acc[i][j]);
        }
    }

    float* out = part + (size_t)blockIdx.z * NTOK * XNC;
#pragma unroll
    for (int i = 0; i < 4; i++) {
        const int m = m0 + tm * 4 + i;
#pragma unroll
        for (int j = 0; j < 4; j++) {
            const int n = n0 + tn * 4 + j;
            if (n < XNC) out[(size_t)m * XNC + n] = acc[i][j];
        }
    }
}

// reduce split-K parts -> xdbl; also emit bf16 xdt (cols 0..63) for dt-GEMM
__launch_bounds__(256)
__global__ void xproj_reduce(const float* __restrict__ part, float* __restrict__ xdbl,
                             unsigned short* __restrict__ xdt)
{
    const int idx = blockIdx.x * 256 + threadIdx.x;          // NTOK*XNC
    float s = 0.f;
#pragma unroll
    for (int z = 0; z < XKS; z++) s += part[(size_t)z * NTOK * XNC + idx];
    xdbl[idx] = s;
    const int m = idx / XNC;
    const int col = idx - m * XNC;
    if (col < 64) xdt[m * 64 + col] = f2bf(s);
}

// ---------------------------------------------------------------------------
// Depthwise causal conv1d (d_conv=4) + SiLU (r16-verified).
// ---------------------------------------------------------------------------
__launch_bounds__(256)
__global__ void conv_silu(const float* __restrict__ xz,
                          const void* __restrict__ conv_w,
                          const void* __restrict__ conv_b,
                          float* __restrict__ xl,
                          const void* __restrict__ Dp)
{
    const int isbf = sniff_bf(Dp);
    const int gid = blockIdx.x * 256 + threadIdx.x;   // (NTOK/4)*(D_INNER/4)
    const int dq  = gid & (D_INNER / 4 - 1);          // channel quad 0..511
    const int tg  = gid >> 9;                         // token group 0..1023
    const int d0  = dq * 4;
    const int tok0 = tg * 4;
    const int l0  = tok0 & (SEQLEN - 1);              // position within sequence

    float w[4][4], bias[4];
#pragma unroll
    for (int dd = 0; dd < 4; dd++) {
        bias[dd] = ldF(conv_b, d0 + dd, isbf);
#pragma unroll
        for (int j = 0; j < 4; j++) w[dd][j] = ldF(conv_w, (d0 + dd) * 4 + j, isbf);
    }

    float4 x[7];
    const float* rowp = xz + (size_t)tok0 * (2 * D_INNER) + d0;
#pragma unroll
    for (int k = 0; k < 7; k++) {
        const int off = k - 3;
        if (l0 + off >= 0)
            x[k] = *(const float4*)(rowp + (ptrdiff_t)off * (2 * D_INNER));
        else
            x[k] = (float4){0.f, 0.f, 0.f, 0.f};
    }

#pragma unroll
    for (int tn = 0; tn < 4; tn++) {
        float a0 = bias[0], a1 = bias[1], a2 = bias[2], a3 = bias[3];
#pragma unroll
        for (int j = 0; j < 4; j++) {
            const float4 v = x[tn + j];
            a0 = fmaf(v.x, w[0][j], a0);
            a1 = fmaf(v.y, w[1][j], a1);
            a2 = fmaf(v.z, w[2][j], a2);
            a3 = fmaf(v.w, w[3][j], a3);
        }
        float4 o;
        o.x = a0 / (1.f + __expf(-a0));
        o.y = a1 / (1.f + __expf(-a1));
        o.z = a2 / (1.f + __expf(-a2));
        o.w = a3 / (1.f + __expf(-a3));
        *(float4*)&xl[(size_t)(tok0 + tn) * D_INNER + d0] = o;
    }
}

// ---------------------------------------------------------------------------
// Scan helpers — n-split (r20): each lane owns 8 states (nh = lane>>5).
// Power-chain trees reproduce mk_dA's exact op order per half -> h bit-identical.
// ---------------------------------------------------------------------------
__device__ __forceinline__ void mk_dA8(float dv, const float An[8], float An0,
                                       int nh, int pw, float* dA)
{
    if (pw) {
        const float E  = __expf(dv * An0);
        const float E2 = E * E;
        const float E4 = E2 * E2;
        const float E8 = E4 * E4;
        if (nh == 0) {   // n = 1..8  (old dA[0..7])
            dA[0] = E;        dA[1] = E2;       dA[2] = E2 * E;   dA[3] = E4;
            dA[4] = E4 * E;   dA[5] = E4 * E2;  dA[6] = dA[5] * E; dA[7] = E8;
        } else {         // n = 9..16 (old dA[8..15])
            dA[0] = E8 * E;   dA[1] = E8 * E2;  dA[2] = dA[1] * E; dA[3] = E8 * E4;
            dA[4] = dA[3] * E; dA[5] = dA[3] * E2; dA[6] = dA[5] * E; dA[7] = E8 * E8;
        }
    } else {
#pragma unroll
        for (int n = 0; n < 8; n++) dA[n] = __expf(dv * An[n]);
    }
}

__device__ __forceinline__ void scan_step8(float h[8], float dv, float uv,
                                           const float Bv[8], const float An[8],
                                           float An0, int nh, int pw)
{
    float dA[8]; mk_dA8(dv, An, An0, nh, pw, dA);
    const float du = dv * uv;
#pragma unroll
    for (int n = 0; n < 8; n++) h[n] = fmaf(dA[n], h[n], du * Bv[n]);
}

__device__ __forceinline__ float scan_step_y8(float h[8], float dv, float uv,
                                              const float Bv[8], const float Cv[8],
                                              const float An[8], float An0,
                                              int nh, int pw, float Dd)
{
    float dA[8]; mk_dA8(dv, An, An0, nh, pw, dA);
    const float du = dv * uv;
    float s[8];
#pragma unroll
    for (int n = 0; n < 8; n++) {
        h[n] = fmaf(dA[n], h[n], du * Bv[n]);
        s[n] = h[n] * Cv[n];
    }
#pragma unroll
    for (int n = 0; n < 4; n++) s[n] += s[n + 4];
    s[0] += s[2]; s[1] += s[3];
    float r = s[0] + s[1];
    r += __shfl_xor(r, 32);          // combine nh halves (in-wave)
    return r + uv * Dd;
}

// ---------------------------------------------------------------------------
// Scan phase 1: per-chunk local scan (h0=0) -> S[b,c,n,d], sumD[b,c,d].
// r20: n-split, 2048 blocks.
// ---------------------------------------------------------------------------
__launch_bounds__(256)
__global__ void scan_chunk(const float* __restrict__ dlt,
                           const float* __restrict__ xl,
                           const float* __restrict__ xdbl,
                           const void* __restrict__ A_log,
                           float* __restrict__ S,
                           float* __restrict__ sumD,
                           const void* __restrict__ Dp)
{
    const int isbf = sniff_bf(Dp);
    const int t    = threadIdx.x;
    const int lane = t & 63;
    const int wv   = t >> 6;
    const int dg   = blockIdx.x & 15;
    const int c    = (blockIdx.x >> 4) & (NCH - 1);
    const int b    = blockIdx.x >> 10;
    const int d    = dg * 128 + wv * 32 + (lane & 31);
    const int nh   = lane >> 5;
    const int n0   = nh * 8;

    const float An0 = -expf(ldF(A_log, (size_t)d * 16, isbf));
    float An[8], h[8];
#pragma unroll
    for (int n = 0; n < 8; n++) {
        An[n] = -expf(ldF(A_log, (size_t)d * 16 + n0 + n, isbf));
        h[n] = 0.f;
    }
    int pw = 1;
#pragma unroll
    for (int n = 0; n < 8; n++)
        pw = pw && (fabsf(An[n] - (float)(n0 + n + 1) * An0)
                    <= 3e-4f * (float)(n0 + n + 1));

    float sd = 0.f;
    const size_t r0 = (size_t)b * SEQLEN + c * LC;

    float dv0 = dlt[r0 * D_INNER + d];
    float uv0 = xl [r0 * D_INNER + d];
    float Bv0[8]; ld8f(&xdbl[r0 * 96 + 64 + n0], Bv0);

    for (int i = 0; i < LC; i += 2) {
        const size_t r1 = r0 + i + 1;
        float dv1 = dlt[r1 * D_INNER + d];
        float uv1 = xl [r1 * D_INNER + d];
        float Bv1[8]; ld8f(&xdbl[r1 * 96 + 64 + n0], Bv1);

        scan_step8(h, dv0, uv0, Bv0, An, An0, nh, pw);
        sd += dv0;

        const size_t r2 = r0 + ((i + 2 < LC) ? (i + 2) : (i + 1));  // clamp
        dv0 = dlt[r2 * D_INNER + d];
        uv0 = xl [r2 * D_INNER + d];
        ld8f(&xdbl[r2 * 96 + 64 + n0], Bv0);

        scan_step8(h, dv1, uv1, Bv1, An, An0, nh, pw);
        sd += dv1;
    }

    const size_t base2 = (((size_t)b * NCH + c) * 16 + n0) * D_INNER + d;
#pragma unroll
    for (int n = 0; n < 8; n++) S[base2 + (size_t)n * D_INNER] = h[n];
    if (nh == 0) sumD[((size_t)b * NCH + c) * D_INNER + d] = sd;
}

// ---------------------------------------------------------------------------
// Scan phase 2: combine chunk states; S rewritten with chunk-START state H0.
// ---------------------------------------------------------------------------
__launch_bounds__(256)
__global__ void scan_combine(float* __restrict__ S,
                             const float* __restrict__ sumD,
                             const void* __restrict__ A_log,
                             const void* __restrict__ Dp)
{
    const int isbf = sniff_bf(Dp);
    const int g = blockIdx.x * 256 + threadIdx.x;
    const int d = g & (D_INNER - 1);
    const int n = (g >> 11) & 15;
    const int b = g >> 15;
    const float An = -expf(ldF(A_log, d * 16 + n, isbf));

    float hs = 0.f;
    float Sc = S[(((size_t)b * NCH + 0) * 16 + n) * D_INNER + d];
    float sd = sumD[((size_t)b * NCH + 0) * D_INNER + d];
    for (int c = 0; c < NCH; c++) {
        const int cn = (c + 1 < NCH) ? c + 1 : c;
        const float Scn = S[(((size_t)b * NCH + cn) * 16 + n) * D_INNER + d];
        const float sdn = sumD[((size_t)b * NCH + cn) * D_INNER + d];
        S[(((size_t)b * NCH + c) * 16 + n) * D_INNER + d] = hs;
        hs = fmaf(__expf(An * sd), hs, Sc);
        Sc = Scn; sd = sdn;
    }
}

// ---------------------------------------------------------------------------
// Scan phase 3: seeded re-scan; y = sum_n h*C; D-skip + silu(z) gate -> bf16 yg.
// r20: n-split, 2048 blocks; y combined via per-half tree + shfl_xor(32).
// ---------------------------------------------------------------------------
__launch_bounds__(256)
__global__ void scan_apply(const float* __restrict__ dlt,
                           const float* __restrict__ xl,
                           const float* __restrict__ xdbl,
                           const float* __restrict__ xz,
                           const void* __restrict__ A_log,
                           const void* __restrict__ Dp,
                           const float* __restrict__ S,   // holds H0
                           unsigned short* __restrict__ yg)
{
    const int isbf = sniff_bf(Dp);
    const int t    = threadIdx.x;
    const int lane = t & 63;
    const int wv   = t >> 6;
    const int dg   = blockIdx.x & 15;
    const int c    = (blockIdx.x >> 4) & (NCH - 1);
    const int b    = blockIdx.x >> 10;
    const int d    = dg * 128 + wv * 32 + (lane & 31);
    const int nh   = lane >> 5;
    const int n0   = nh * 8;

    const float An0 = -expf(ldF(A_log, (size_t)d * 16, isbf));
    float An[8], h[8];
    const size_t base2 = (((size_t)b * NCH + c) * 16 + n0) * D_INNER + d;
#pragma unroll
    for (int n = 0; n < 8; n++) {
        An[n] = -expf(ldF(A_log, (size_t)d * 16 + n0 + n, isbf));
        h[n] = S[base2 + (size_t)n * D_INNER];
    }
    int pw = 1;
#pragma unroll
    for (int n = 0; n < 8; n++)
        pw = pw && (fabsf(An[n] - (float)(n0 + n + 1) * An0)
                    <= 3e-4f * (float)(n0 + n + 1));

    const float Dd = ldF(Dp, d, isbf);
    const size_t r0 = (size_t)b * SEQLEN + c * LC;

    float dv0 = dlt[r0 * D_INNER + d];
    float uv0 = xl [r0 * D_INNER + d];
    float zv0 = xz [r0 * (2 * D_INNER) + D_INNER + d];
    float Bv0[8], Cv0[8];
    ld8f(&xdbl[r0 * 96 + 64 + n0], Bv0);
    ld8f(&xdbl[r0 * 96 + 80 + n0], Cv0);

    for (int i = 0; i < LC; i += 2) {
        const size_t ra = r0 + i + 1;
        float dv1 = dlt[ra * D_INNER + d];
        float uv1 = xl [ra * D_INNER + d];
        float zv1 = xz [ra * (2 * D_INNER) + D_INNER + d];
        float Bv1[8], Cv1[8];
        ld8f(&xdbl[ra * 96 + 64 + n0], Bv1);
        ld8f(&xdbl[ra * 96 + 80 + n0], Cv1);

        {
            const float yv = scan_step_y8(h, dv0, uv0, Bv0, Cv0, An, An0, nh, pw, Dd);
            if (nh == 0)
                yg[(r0 + i) * D_INNER + d] = f2bf(yv * (zv0 / (1.f + __expf(-zv0))));
        }

        const size_t rb = r0 + ((i + 2 < LC) ? (i + 2) : (i + 1));  // clamp
        dv0 = dlt[rb * D_INNER + d];
        uv0 = xl [rb * D_INNER + d];
        zv0 = xz [rb * (2 * D_INNER) + D_INNER + d];
        ld8f(&xdbl[rb * 96 + 64 + n0], Bv0);
        ld8f(&xdbl[rb * 96 + 80 + n0], Cv0);

        {
            const float yv = scan_step_y8(h, dv1, uv1, Bv1, Cv1, An, An0, nh, pw, Dd);
            if (nh == 0)
                yg[ra * D_INNER + d] = f2bf(yv * (zv1 / (1.f + __expf(-zv1))));
        }
    }
}

// ---------------------------------------------------------------------------
extern "C" void kernel_launch(void* const* d_in, const int* in_sizes, int n_in,
                              void* d_out, int out_size, void* d_ws, size_t ws_size,
                              hipStream_t stream)
{
    const void* hidden     = d_in[0]; // f32
    const void* in_proj_w  = d_in[1];
    const void* conv_w     = d_in[2];
    const void* conv_b     = d_in[3];
    const void* x_proj_w   = d_in[4];
    const void* dt_proj_w  = d_in[5];
    const void* dt_proj_b  = d_in[6];
    const void* A_log      = d_in[7];
    const void* Dp         = d_in[8];
    const void* out_proj_w = d_in[9];

    char* ws = (char*)d_ws;
    float*          xz   = (float*)(ws);                        // [4096,4096]  64 MB
    float*          xl   = (float*)(ws + 67108864ull);          // [4096,2048]  32 MB
    float*          xdbl = (float*)(ws + 100663296ull);         // [4096,96]   1.5 MB
    float*          dlt  = (float*)(ws + 102236160ull);         // [4096,2048]  32 MB (step 4)
    unsigned short* yg   = (unsigned short*)(ws + 135790592ull);// [4096,2048] bf16 16 MB
    unsigned short* opwB = (unsigned short*)(ws + 152567808ull);// out_proj_w bf16 4 MB
    unsigned short* xdt  = (unsigned short*)(ws + 156762112ull);// [4096,64] bf16 512 KB (hole)
    unsigned short* dtwB = (unsigned short*)(ws + 157286400ull);// [2048,64] bf16 256 KB (hole)
    float*          S    = (float*)(ws + 169345280ull);         // 16 MB
    float*          sumD = (float*)(ws + 186122496ull);         // 1 MB
    int*            dmap = (int*)  (ws + 187171072ull);         // 256 B probe LUT
    // transient occupants of the dlt region (dead before dt-GEMM writes dlt):
    unsigned short* hidB  = (unsigned short*)(ws + 102236160ull);              // 8 MB
    unsigned short* ipwB  = (unsigned short*)(ws + 102236160ull + 8388608ull); // 8 MB
    float*          xpart = (float*)(ws + 102236160ull);        // [8,4096,96] 12.6 MB

    dim3 blk(256);

    // 0) f32 -> bf16 copies for MFMA operands + block-0 MFMA layout probe
    cvt_all<<<dim3(CVT_TOT / (256 * 8)), blk, 0, stream>>>(
        hidden, in_proj_w, out_proj_w, dt_proj_w, hidB, ipwB, opwB, dtwB, Dp, dmap);

    // 1) xz = hidden @ in_proj_w^T   [4096,4096]  (bf16 MFMA, 256^2 8-phase)
    hipFuncSetAttribute((const void*)gemm1_8ph,
                        hipFuncAttributeMaxDynamicSharedMemorySize, 131072);
    gemm1_8ph<<<dim3((NTOK / 256) * (2 * D_INNER / 256)), dim3(512), 131072, stream>>>(
        hidB, ipwB, xz, NTOK, 2 * D_INNER, D_MODEL, dmap);

    // 2) xl = silu(causal_conv1d(x) + conv_b)  (4-tok x 4-ch blocks)
    conv_silu<<<dim3((NTOK / 4) * (D_INNER / 4) / 256), blk, 0, stream>>>(
        xz, conv_w, conv_b, xl, Dp);

    // 3) xdbl = xl @ x_proj_w^T  via split-K  (+ fused bf16 xdt pack)
    xproj_splitk<<<dim3(2, 64, XKS), blk, 0, stream>>>(
        xl, (const float*)x_proj_w, xpart);
    xproj_reduce<<<dim3(NTOK * XNC / 256), blk, 0, stream>>>(xpart, xdbl, xdt);

    // 4) delta = softplus(dt @ dt_proj_w^T + dt_proj_b)  (single-stage K=64)
    gemm_dt<<<dim3((NTOK / 128) * (D_INNER / 128)), blk, 0, stream>>>(
        xdt, dtwB, dlt, dmap, dt_proj_b, Dp);

    // 5) chunked parallel scan + D-skip + silu(z) gate -> yg (bf16)
    //    r20: n-split grids (2048 blocks)
    scan_chunk<<<dim3(BATCH * NCH * (D_INNER / 128)), blk, 0, stream>>>(
        dlt, xl, xdbl, A_log, S, sumD, Dp);
    scan_combine<<<dim3(BATCH * 16 * D_INNER / 256), blk, 0, stream>>>(
        S, sumD, A_log, Dp);
    scan_apply<<<dim3(BATCH * NCH * (D_INNER / 128)), blk, 0, stream>>>(
        dlt, xl, xdbl, xz, A_log, Dp, S, yg);

    // 6) out = yg @ out_proj_w^T -> f32 d_out  (2-phase counted pipeline)
    gemm_op_2ph<<<dim3((NTOK / 128) * (D_MODEL / 64)), blk, 0, stream>>>(
        yg, opwB, (float*)d_out, dmap);
}

// Round 9
// 311.998 us; speedup vs baseline: 1.0794x; 1.0794x over previous
//
#include <hip/hip_runtime.h>

#define D_MODEL 1024
#define D_STATE 16
#define D_CONV  4
#define D_INNER 2048
#define DT_RANK 64
#define BATCH   2
#define SEQLEN  2048
#define NTOK    (BATCH * SEQLEN)   // 4096
#define NCH     64                 // scan chunks
#define LC      (SEQLEN / NCH)     // 32 steps per chunk
#define XKS     8                  // x_proj split-K factor
#define XNC     96                 // dt_rank + 2*d_state

// FACTS (r2-r12): inputs f32; d_out read as f32; bf16 internal copies for MFMA;
// async global_load_lds verified (r9); out_proj split-K regressed (r10); ws peak
// <= 187,171,328 B (r11 abort); dt_proj MFMA verified (r12). r13: out_proj BN=64
// + M-major. r14: in_proj 256^2/BK=64 8-phase — win. r15: scan power-chain —
// win. r16: conv 4x4 blocks — win. r17: out_proj 2-phase counted pipeline — win.
// r18 REGRESSED (conv fused into gemm1: spills + barrier skew). r19: revert +
// gemm_dt single-stage + gate __expf — win (316.8, best). r20/r21 REGRESSED
// (scan n-split 336.8: scan is LOAD-ISSUE-bound, not VALU-chain-bound — the
// split doubled redundant dv/uv/zv loads per element, 11 -> 14 load issues,
// + shfl dependency; occupancy gain irrelevant). r22 (this round): scan trio
// reverted to r19 16-state form exactly; keep the r20 probe-fold into cvt_all
// (verified harmless, 10 dispatches).

// ---------- bf16 helpers ----------
__device__ __forceinline__ float bf2f(unsigned short v) {
    union { unsigned int u; float f; } c; c.u = ((unsigned int)v) << 16; return c.f;
}
__device__ __forceinline__ unsigned short f2bf(float f) {
    union { unsigned int u; float f; } c; c.f = f;
    unsigned int r = c.u + 0x7FFF + ((c.u >> 16) & 1);   // RNE
    return (unsigned short)(r >> 16);
}

__device__ __forceinline__ int sniff_bf(const void* Dp) {
    return (((const unsigned int*)Dp)[0] == 0x3F803F80u) ? 1 : 0;
}

__device__ __forceinline__ float ldF(const void* p, size_t idx, int isbf) {
    return isbf ? bf2f(((const unsigned short*)p)[idx]) : ((const float*)p)[idx];
}
__device__ __forceinline__ void ld16f(const float* p, float* o) {
#pragma unroll
    for (int q = 0; q < 4; q++) {
        float4 v = *(const float4*)(p + 4 * q);
        o[4 * q + 0] = v.x; o[4 * q + 1] = v.y; o[4 * q + 2] = v.z; o[4 * q + 3] = v.w;
    }
}

typedef __attribute__((ext_vector_type(8))) __bf16 bf16x8;
typedef __attribute__((ext_vector_type(4))) float  f32x4;

// ---------------------------------------------------------------------------
// MFMA layout probe (r8-verified), block-0 section of cvt_all.
// dmap[lane*4+r] = row | col<<4 in loader coords.
// ---------------------------------------------------------------------------
__device__ void probe_dmap_block(int t, int* __restrict__ dmap)
{
    __shared__ alignas(16) unsigned short PAs[16 * 32];
    __shared__ alignas(16) unsigned short PBs[16 * 32];
    const int q = (t & 63) >> 4, l15 = t & 15;

    if (t < 64)
        for (int idx = t; idx < 512; idx += 64) {
            PAs[idx] = f2bf((float)(idx >> 5));
            PBs[idx] = f2bf(0.03125f);
        }
    __syncthreads();
    f32x4 acc1 = {0.f, 0.f, 0.f, 0.f};
    if (t < 64) {
        bf16x8 a1 = *(const bf16x8*)&PAs[l15 * 32 + q * 8];
        bf16x8 b1 = *(const bf16x8*)&PBs[l15 * 32 + q * 8];
        acc1 = __builtin_amdgcn_mfma_f32_16x16x32_bf16(a1, b1, acc1, 0, 0, 0);
    }
    __syncthreads();
    if (t < 64)
        for (int idx = t; idx < 512; idx += 64) {
            PAs[idx] = f2bf(0.03125f);
            PBs[idx] = f2bf((float)(idx >> 5));
        }
    __syncthreads();
    if (t < 64) {
        bf16x8 a2 = *(const bf16x8*)&PAs[l15 * 32 + q * 8];
        bf16x8 b2 = *(const bf16x8*)&PBs[l15 * 32 + q * 8];
        f32x4 acc2 = {0.f, 0.f, 0.f, 0.f};
        acc2 = __builtin_amdgcn_mfma_f32_16x16x32_bf16(a2, b2, acc2, 0, 0, 0);
#pragma unroll
        for (int r = 0; r < 4; r++) {
            int ma = (int)(acc1[r] + 0.5f);
            int nb = (int)(acc2[r] + 0.5f);
            if (ma < 0 || ma > 15 || nb < 0 || nb > 15) { ma = q * 4 + r; nb = l15; }
            dmap[t * 4 + r] = ma | (nb << 4);
        }
    }
}

// ---------------------------------------------------------------------------
// Fused bf16 conversion for the 4 MFMA operand copies (8 elems/thread)
// + block-0 MFMA layout probe.
// ---------------------------------------------------------------------------
#define CVT_N0 (NTOK * D_MODEL)        // hidden   4,194,304
#define CVT_N1 (2 * D_INNER * D_MODEL) // in_proj  4,194,304
#define CVT_N2 (D_MODEL * D_INNER)     // out_proj 2,097,152
#define CVT_N3 (D_INNER * DT_RANK)     // dt_proj    131,072
#define CVT_TOT (CVT_N0 + CVT_N1 + CVT_N2 + CVT_N3)

__device__ __forceinline__ void cvt8(const void* in, unsigned short* out,
                                     size_t e0, int isbf)
{
    if (isbf) {
        *(uint4*)(out + e0) = *(const uint4*)((const unsigned short*)in + e0);
    } else {
        const float* f = (const float*)in + e0;
        float4 a = *(const float4*)f;
        float4 b = *(const float4*)(f + 4);
        ushort4 o0 = { f2bf(a.x), f2bf(a.y), f2bf(a.z), f2bf(a.w) };
        ushort4 o1 = { f2bf(b.x), f2bf(b.y), f2bf(b.z), f2bf(b.w) };
        *(ushort4*)(out + e0)     = o0;
        *(ushort4*)(out + e0 + 4) = o1;
    }
}

__launch_bounds__(256)
__global__ void cvt_all(const void* __restrict__ hid, const void* __restrict__ ipw,
                        const void* __restrict__ opw, const void* __restrict__ dtw,
                        unsigned short* __restrict__ hidB, unsigned short* __restrict__ ipwB,
                        unsigned short* __restrict__ opwB, unsigned short* __restrict__ dtwB,
                        const void* __restrict__ Dp, int* __restrict__ dmap)
{
    if (blockIdx.x == 0) probe_dmap_block(threadIdx.x, dmap);

    const int isbf = sniff_bf(Dp);
    size_t e = ((size_t)blockIdx.x * 256 + threadIdx.x) * 8;
    if (e < CVT_N0) { cvt8(hid, hidB, e, isbf); return; }
    e -= CVT_N0;
    if (e < CVT_N1) { cvt8(ipw, ipwB, e, isbf); return; }
    e -= CVT_N1;
    if (e < CVT_N2) { cvt8(opw, opwB, e, isbf); return; }
    e -= CVT_N2;
    if (e < CVT_N3) { cvt8(dtw, dtwB, e, isbf); }
}

// ---------------------------------------------------------------------------
__device__ __forceinline__ void gl2lds16(const void* g, void* l) {
    __builtin_amdgcn_global_load_lds(
        (const __attribute__((address_space(1))) unsigned int*)g,
        (__attribute__((address_space(3))) unsigned int*)l,
        16, 0, 0);
}

// ===========================================================================
// in_proj GEMM: 256x256 tile, BK=64, 8 waves, 8-phase schedule (r14-verified).
// ===========================================================================
__device__ __forceinline__ void stage_half(const unsigned short* __restrict__ G,
                                           int grow0, int K, int k0,
                                           unsigned short* ldsAB, int half, int t)
{
    const int r8  = t >> 3;                 // 0..63: row within 64-row group
    const int c8  = t & 7;                  // physical 16B slot
    const int swz = (c8 ^ (r8 & 7)) << 3;   // logical col in shorts
#pragma unroll
    for (int j = 0; j < 2; j++) {
        const int row = half * 128 + j * 64 + r8;
        gl2lds16(&G[(size_t)(grow0 + row) * K + k0 + swz],
                 &ldsAB[row * 64 + c8 * 8]);
    }
}

__device__ __forceinline__ bf16x8 ldsfrag(const unsigned short* p, int row, int slot) {
    return *(const bf16x8*)&p[row * 64 + ((slot ^ (row & 7)) << 3)];
}

__launch_bounds__(512)
__global__ void gemm1_8ph(const unsigned short* __restrict__ A,
                          const unsigned short* __restrict__ B,
                          float* __restrict__ C,
                          int M, int N, int K,
                          const int* __restrict__ dmap)
{
    extern __shared__ __align__(16) unsigned short lds[];
    unsigned short* A0l = lds;              // buf0 A [256][64]
    unsigned short* B0l = lds + 16384;      // buf0 B
    unsigned short* A1l = lds + 32768;      // buf1 A
    unsigned short* B1l = lds + 49152;      // buf1 B

    const int t    = threadIdx.x;
    const int lane = t & 63;
    const int w    = t >> 6;
    const int wm   = (w >> 2) * 128, wn = (w & 3) * 64;
    const int q    = lane >> 4, l15 = lane & 15;

    const int nbn  = N >> 8;
    const int nwg  = (M >> 8) * nbn;        // 256 here: % 8 == 0 -> bijective
    const int orig = blockIdx.x;
    const int wg   = (orig & 7) * (nwg >> 3) + (orig >> 3);
    const int bm   = wg / nbn, bn = wg % nbn;
    const int m0   = bm << 8, n0 = bn << 8;
    const int NT   = K >> 6;

    int mp[4];
#pragma unroll
    for (int r = 0; r < 4; r++) mp[r] = dmap[lane * 4 + r];

    f32x4 acc[8][4];
#pragma unroll
    for (int i = 0; i < 8; i++)
#pragma unroll
        for (int j = 0; j < 4; j++) acc[i][j] = (f32x4){0.f, 0.f, 0.f, 0.f};

    // ---- prologue: tile0 {B,A}, tile1 {B}; wait oldest 8 (= tile0 complete)
    stage_half(B, n0, K, 0, B0l, 0, t);
    stage_half(B, n0, K, 0, B0l, 1, t);
    stage_half(A, m0, K, 0, A0l, 0, t);
    stage_half(A, m0, K, 0, A0l, 1, t);
    {
        const int k1 = (NT > 1 ? 64 : 0);
        stage_half(B, n0, K, k1, B1l, 0, t);
        stage_half(B, n0, K, k1, B1l, 1, t);
    }
    asm volatile("s_waitcnt vmcnt(4)" ::: "memory");
    __builtin_amdgcn_s_barrier();

#pragma unroll 2
    for (int tt = 0; tt < NT; ++tt) {
        const int p = tt & 1;
        const unsigned short* Ac = p ? A1l : A0l;
        const unsigned short* Bc = p ? B1l : B0l;
        unsigned short* Anx = p ? A0l : A1l;   // tile tt+1 A (other buf)
        unsigned short* Bnx = p ? B1l : B0l;   // tile tt+2 B (same buf, dead after ph1)
        const int kA = (tt + 1 < NT ? tt + 1 : 0) << 6;
        const int kB = (tt + 2 < NT ? tt + 2 : 0) << 6;

        bf16x8 af[4][2], b0r[2][2], b1r[2][2];

        // ---------------- phase 0: quadrant (mh0, nh0)
#pragma unroll
        for (int i = 0; i < 4; i++)
#pragma unroll
            for (int ks = 0; ks < 2; ks++)
                af[i][ks] = ldsfrag(Ac, wm + i * 16 + l15, ks * 4 + q);
#pragma unroll
        for (int j = 0; j < 2; j++)
#pragma unroll
            for (int ks = 0; ks < 2; ks++)
                b0r[j][ks] = ldsfrag(Bc, wn + j * 16 + l15, ks * 4 + q);
        stage_half(A, m0, K, kA, Anx, 0, t);
        asm volatile("" ::: "memory");
        __builtin_amdgcn_s_barrier();
        __builtin_amdgcn_s_setprio(1);
#pragma unroll
        for (int i = 0; i < 4; i++)
#pragma unroll
            for (int j = 0; j < 2; j++)
#pragma unroll
                for (int ks = 0; ks < 2; ks++)
                    acc[i][j] = __builtin_amdgcn_mfma_f32_16x16x32_bf16(
                        af[i][ks], b0r[j][ks], acc[i][j], 0, 0, 0);
        __builtin_amdgcn_s_setprio(0);
        asm volatile("" ::: "memory");
        __builtin_amdgcn_s_barrier();

        // ---------------- phase 1: quadrant (mh0, nh1)
#pragma unroll
        for (int j = 0; j < 2; j++)
#pragma unroll
            for (int ks = 0; ks < 2; ks++)
                b1r[j][ks] = ldsfrag(Bc, wn + 32 + j * 16 + l15, ks * 4 + q);
        stage_half(A, m0, K, kA, Anx, 1, t);
        asm volatile("" ::: "memory");
        __builtin_amdgcn_s_barrier();
        __builtin_amdgcn_s_setprio(1);
#pragma unroll
        for (int i = 0; i < 4; i++)
#pragma unroll
            for (int j = 0; j < 2; j++)
#pragma unroll
                for (int ks = 0; ks < 2; ks++)
                    acc[i][2 + j] = __builtin_amdgcn_mfma_f32_16x16x32_bf16(
                        af[i][ks], b1r[j][ks], acc[i][2 + j], 0, 0, 0);
        __builtin_amdgcn_s_setprio(0);
        asm volatile("" ::: "memory");
        __builtin_amdgcn_s_barrier();

        // ---------------- phase 2: quadrant (mh1, nh1)
#pragma unroll
        for (int i = 0; i < 4; i++)
#pragma unroll
            for (int ks = 0; ks < 2; ks++)
                af[i][ks] = ldsfrag(Ac, wm + 64 + i * 16 + l15, ks * 4 + q);
        stage_half(B, n0, K, kB, Bnx, 0, t);
        asm volatile("" ::: "memory");
        __builtin_amdgcn_s_barrier();
        __builtin_amdgcn_s_setprio(1);
#pragma unroll
        for (int i = 0; i < 4; i++)
#pragma unroll
            for (int j = 0; j < 2; j++)
#pragma unroll
                for (int ks = 0; ks < 2; ks++)
                    acc[4 + i][2 + j] = __builtin_amdgcn_mfma_f32_16x16x32_bf16(
                        af[i][ks], b1r[j][ks], acc[4 + i][2 + j], 0, 0, 0);
        __builtin_amdgcn_s_setprio(0);
        asm volatile("" ::: "memory");
        __builtin_amdgcn_s_barrier();

        // ---------------- phase 3: quadrant (mh1, nh0)
        stage_half(B, n0, K, kB, Bnx, 1, t);
        asm volatile("" ::: "memory");
        __builtin_amdgcn_s_barrier();
        __builtin_amdgcn_s_setprio(1);
#pragma unroll
        for (int i = 0; i < 4; i++)
#pragma unroll
            for (int j = 0; j < 2; j++)
#pragma unroll
                for (int ks = 0; ks < 2; ks++)
                    acc[4 + i][j] = __builtin_amdgcn_mfma_f32_16x16x32_bf16(
                        af[i][ks], b0r[j][ks], acc[4 + i][j], 0, 0, 0);
        __builtin_amdgcn_s_setprio(0);
        asm volatile("s_waitcnt vmcnt(4)" ::: "memory");
        __builtin_amdgcn_s_barrier();
    }

    // ---- epilogue
#pragma unroll
    for (int i = 0; i < 8; i++) {
#pragma unroll
        for (int r = 0; r < 4; r++) {
            const int mo = mp[r] & 15, no = mp[r] >> 4;
            const int m = m0 + wm + i * 16 + mo;
#pragma unroll
            for (int j = 0; j < 4; j++) {
                const int n = n0 + wn + j * 16 + no;
                C[(size_t)m * N + n] = acc[i][j][r];
            }
        }
    }
}

// ===========================================================================
// out_proj GEMM: 128x64 tile, BK=64, 4 waves, 2-phase counted pipeline
// (r17-verified). T2 XOR-swizzle. Grid 512 = 2 blocks/CU.
// ===========================================================================
__device__ __forceinline__ void stage_op(const unsigned short* __restrict__ A,
                                         const unsigned short* __restrict__ B,
                                         int m0, int n0, int K, int k0,
                                         unsigned short* Al, unsigned short* Bl, int t)
{
    const int r   = t >> 3;                 // 0..31
    const int c8  = t & 7;                  // physical 16B slot
    const int swz = (c8 ^ (r & 7)) << 3;    // logical col in shorts
#pragma unroll
    for (int j = 0; j < 4; j++) {           // A rows 0..127
        const int row = j * 32 + r;
        gl2lds16(&A[(size_t)(m0 + row) * K + k0 + swz], &Al[row * 64 + c8 * 8]);
    }
#pragma unroll
    for (int j = 0; j < 2; j++) {           // B rows 0..63
        const int row = j * 32 + r;
        gl2lds16(&B[(size_t)(n0 + row) * K + k0 + swz], &Bl[row * 64 + c8 * 8]);
    }
}

__launch_bounds__(256)
__global__ void gemm_op_2ph(const unsigned short* __restrict__ A,   // yg [4096][2048]
                            const unsigned short* __restrict__ B,   // opwB [1024][2048]
                            float* __restrict__ C,                  // [4096][1024]
                            const int* __restrict__ dmap)
{
    constexpr int M = NTOK, N = D_MODEL, K = D_INNER;
    constexpr int NT = K / 64;               // 32
    __shared__ alignas(16) unsigned short Al[2][128 * 64];  // 32 KB
    __shared__ alignas(16) unsigned short Bl[2][64 * 64];   // 16 KB

    const int t    = threadIdx.x;
    const int lane = t & 63;
    const int w    = t >> 6;
    const int wm   = (w >> 1) * 64, wn = (w & 1) * 32;
    const int q    = lane >> 4, l15 = lane & 15;

    const int nbn  = N / 64;                 // 16
    const int nwg  = (M / 128) * nbn;        // 512, % 8 == 0
    const int orig = blockIdx.x;
    const int wg   = (orig & 7) * (nwg >> 3) + (orig >> 3);
    const int bm   = wg / nbn, bn = wg % nbn;
    const int m0   = bm * 128, n0 = bn * 64;

    int mp[4];
#pragma unroll
    for (int r = 0; r < 4; r++) mp[r] = dmap[lane * 4 + r];

    f32x4 acc[4][2];
#pragma unroll
    for (int i = 0; i < 4; i++)
#pragma unroll
        for (int j = 0; j < 2; j++) acc[i][j] = (f32x4){0.f, 0.f, 0.f, 0.f};

    stage_op(A, B, m0, n0, K, 0, Al[0], Bl[0], t);
    asm volatile("s_waitcnt vmcnt(0)" ::: "memory");
    __builtin_amdgcn_s_barrier();

#pragma unroll 2
    for (int tt = 0; tt < NT - 1; ++tt) {
        const int cur = tt & 1;
        stage_op(A, B, m0, n0, K, (tt + 1) * 64, Al[cur ^ 1], Bl[cur ^ 1], t);

        bf16x8 af[4][2], bfr[2][2];
#pragma unroll
        for (int i = 0; i < 4; i++)
#pragma unroll
            for (int ks = 0; ks < 2; ks++)
                af[i][ks] = ldsfrag(Al[cur], wm + i * 16 + l15, ks * 4 + q);
#pragma unroll
        for (int j = 0; j < 2; j++)
#pragma unroll
            for (int ks = 0; ks < 2; ks++)
                bfr[j][ks] = ldsfrag(Bl[cur], wn + j * 16 + l15, ks * 4 + q);
        __builtin_amdgcn_s_setprio(1);
#pragma unroll
        for (int i = 0; i < 4; i++)
#pragma unroll
            for (int j = 0; j < 2; j++)
#pragma unroll
                for (int ks = 0; ks < 2; ks++)
                    acc[i][j] = __builtin_amdgcn_mfma_f32_16x16x32_bf16(
                        af[i][ks], bfr[j][ks], acc[i][j], 0, 0, 0);
        __builtin_amdgcn_s_setprio(0);
        asm volatile("s_waitcnt vmcnt(0)" ::: "memory");
        __builtin_amdgcn_s_barrier();
    }

    {
        const int cur = (NT - 1) & 1;
        bf16x8 af[4][2], bfr[2][2];
#pragma unroll
        for (int i = 0; i < 4; i++)
#pragma unroll
            for (int ks = 0; ks < 2; ks++)
                af[i][ks] = ldsfrag(Al[cur], wm + i * 16 + l15, ks * 4 + q);
#pragma unroll
        for (int j = 0; j < 2; j++)
#pragma unroll
            for (int ks = 0; ks < 2; ks++)
                bfr[j][ks] = ldsfrag(Bl[cur], wn + j * 16 + l15, ks * 4 + q);
#pragma unroll
        for (int i = 0; i < 4; i++)
#pragma unroll
            for (int j = 0; j < 2; j++)
#pragma unroll
                for (int ks = 0; ks < 2; ks++)
                    acc[i][j] = __builtin_amdgcn_mfma_f32_16x16x32_bf16(
                        af[i][ks], bfr[j][ks], acc[i][j], 0, 0, 0);
    }

#pragma unroll
    for (int i = 0; i < 4; i++) {
#pragma unroll
        for (int r = 0; r < 4; r++) {
            const int mo = mp[r] & 15, no = mp[r] >> 4;
            const int m = m0 + wm + i * 16 + mo;
#pragma unroll
            for (int j = 0; j < 2; j++) {
                const int n = n0 + wn + j * 16 + no;
                C[(size_t)m * N + n] = acc[i][j][r];
            }
        }
    }
}

// ===========================================================================
// dt_proj GEMM (K=64): 128x128 tile, single 32KB stage (r19-verified).
// ===========================================================================
__launch_bounds__(256)
__global__ void gemm_dt(const unsigned short* __restrict__ A,   // xdt [4096][64]
                        const unsigned short* __restrict__ B,   // dtwB [2048][64]
                        float* __restrict__ C,                  // dlt [4096][2048]
                        const int* __restrict__ dmap,
                        const void* __restrict__ bias,
                        const void* __restrict__ Dp)
{
    constexpr int M = NTOK, N = D_INNER, K = DT_RANK;   // 4096, 2048, 64
    __shared__ alignas(16) unsigned short Al[128 * 64]; // 16 KB
    __shared__ alignas(16) unsigned short Bl[128 * 64]; // 16 KB

    const int t    = threadIdx.x;
    const int lane = t & 63;
    const int w    = t >> 6;
    const int wm   = (w >> 1) * 64, wn = (w & 1) * 64;
    const int q    = lane >> 4, l15 = lane & 15;

    const int nbn  = N / 128;                // 16
    const int nwg  = (M / 128) * nbn;        // 512, % 8 == 0 -> bijective
    const int orig = blockIdx.x;
    const int wg   = (orig & 7) * (nwg >> 3) + (orig >> 3);
    const int bm   = wg / nbn, bn = wg % nbn;
    const int m0   = bm * 128, n0 = bn * 128;

    int mp[4];
#pragma unroll
    for (int r = 0; r < 4; r++) mp[r] = dmap[lane * 4 + r];

    {
        const int r   = t >> 3;              // 0..31
        const int c8  = t & 7;
        const int swz = (c8 ^ (r & 7)) << 3;
#pragma unroll
        for (int j = 0; j < 4; j++) {
            const int row = j * 32 + r;
            gl2lds16(&A[(size_t)(m0 + row) * K + swz], &Al[row * 64 + c8 * 8]);
            gl2lds16(&B[(size_t)(n0 + row) * K + swz], &Bl[row * 64 + c8 * 8]);
        }
    }
    asm volatile("s_waitcnt vmcnt(0)" ::: "memory");
    __builtin_amdgcn_s_barrier();

    f32x4 acc[4][4];
#pragma unroll
    for (int i = 0; i < 4; i++)
#pragma unroll
        for (int j = 0; j < 4; j++) acc[i][j] = (f32x4){0.f, 0.f, 0.f, 0.f};

    bf16x8 af[4][2], bfr[4][2];
#pragma unroll
    for (int i = 0; i < 4; i++)
#pragma unroll
        for (int ks = 0; ks < 2; ks++)
            af[i][ks] = ldsfrag(Al, wm + i * 16 + l15, ks * 4 + q);
#pragma unroll
    for (int j = 0; j < 4; j++)
#pragma unroll
        for (int ks = 0; ks < 2; ks++)
            bfr[j][ks] = ldsfrag(Bl, wn + j * 16 + l15, ks * 4 + q);
#pragma unroll
    for (int i = 0; i < 4; i++)
#pragma unroll
        for (int j = 0; j < 4; j++)
#pragma unroll
            for (int ks = 0; ks < 2; ks++)
                acc[i][j] = __builtin_amdgcn_mfma_f32_16x16x32_bf16(
                    af[i][ks], bfr[j][ks], acc[i][j], 0, 0, 0);

    const int isbf = sniff_bf(Dp);
#pragma unroll
    for (int i = 0; i < 4; i++) {
#pragma unroll
        for (int r = 0; r < 4; r++) {
            const int mo = mp[r] & 15, no = mp[r] >> 4;
            const int m = m0 + wm + i * 16 + mo;
#pragma unroll
            for (int j = 0; j < 4; j++) {
                const int n = n0 + wn + j * 16 + no;
                float v = acc[i][j][r] + ldF(bias, n, isbf);
                v = fmaxf(v, 0.f) + __logf(1.f + __expf(-fabsf(v)));   // softplus
                C[(size_t)m * N + n] = v;
            }
        }
    }
}

// ---------------------------------------------------------------------------
// x_proj split-K: part[z][M][96] = xl[:, zKc:(z+1)Kc] @ x_proj_w[:, zKc:]^T
// ---------------------------------------------------------------------------
__launch_bounds__(256)
__global__ void xproj_splitk(const float* __restrict__ A,   // xl [4096,2048]
                             const float* __restrict__ B,   // x_proj_w [96,2048]
                             float* __restrict__ part)      // [XKS,4096,96]
{
    __shared__ alignas(16) float As[16][68];
    __shared__ alignas(16) float Bs[16][68];
    const int t  = threadIdx.x;
    const int m0 = blockIdx.y * 64, n0 = blockIdx.x * 64;
    const int koff = blockIdx.z * (D_INNER / XKS);           // 256-wide K chunk
    const int lr = t >> 2;
    const int lk = (t & 3) * 4;
    const int tm = t >> 4, tn = t & 15;

    float acc[4][4];
#pragma unroll
    for (int i = 0; i < 4; i++)
#pragma unroll
        for (int j = 0; j < 4; j++) acc[i][j] = 0.f;

    for (int k0 = koff; k0 < koff + D_INNER / XKS; k0 += 16) {
        float av[4], bv[4];
        {
            const int m = m0 + lr;
            float4 p = *(const float4*)&A[(size_t)m * D_INNER + k0 + lk];
            av[0] = p.x; av[1] = p.y; av[2] = p.z; av[3] = p.w;
        }
        {
            const int n = n0 + lr;
            if (n < XNC) {
                float4 p = *(const float4*)&B[(size_t)n * D_INNER + k0 + lk];
                bv[0] = p.x; bv[1] = p.y; bv[2] = p.z; bv[3] = p.w;
            } else { bv[0] = bv[1] = bv[2] = bv[3] = 0.f; }
        }
        __syncthreads();
#pragma unroll
        for (int i = 0; i < 4; i++) { As[lk + i][lr] = av[i]; Bs[lk + i][lr] = bv[i]; }
        __syncthreads();

#pragma unroll
        for (int kk = 0; kk < 16; kk++) {
            float4 a = *(const float4*)&As[kk][tm * 4];
            float4 b = *(const float4*)&Bs[kk][tn * 4];
            float aa[4] = { a.x, a.y, a.z, a.w };
            float bb[4] = { b.x, b.y, b.z, b.w };
#pragma unroll
            for (int i = 0; i < 4; i++)
#pragma unroll
                for (int j = 0; j < 4; j++) acc[i][j] = fmaf(aa[i], bb[j], acc[i][j]);
        }
    }

    float* out = part + (size_t)blockIdx.z * NTOK * XNC;
#pragma unroll
    for (int i = 0; i < 4; i++) {
        const int m = m0 + tm * 4 + i;
#pragma unroll
        for (int j = 0; j < 4; j++) {
            const int n = n0 + tn * 4 + j;
            if (n < XNC) out[(size_t)m * XNC + n] = acc[i][j];
        }
    }
}

// reduce split-K parts -> xdbl; also emit bf16 xdt (cols 0..63) for dt-GEMM
__launch_bounds__(256)
__global__ void xproj_reduce(const float* __restrict__ part, float* __restrict__ xdbl,
                             unsigned short* __restrict__ xdt)
{
    const int idx = blockIdx.x * 256 + threadIdx.x;          // NTOK*XNC
    float s = 0.f;
#pragma unroll
    for (int z = 0; z < XKS; z++) s += part[(size_t)z * NTOK * XNC + idx];
    xdbl[idx] = s;
    const int m = idx / XNC;
    const int col = idx - m * XNC;
    if (col < 64) xdt[m * 64 + col] = f2bf(s);
}

// ---------------------------------------------------------------------------
// Depthwise causal conv1d (d_conv=4) + SiLU (r16-verified).
// ---------------------------------------------------------------------------
__launch_bounds__(256)
__global__ void conv_silu(const float* __restrict__ xz,
                          const void* __restrict__ conv_w,
                          const void* __restrict__ conv_b,
                          float* __restrict__ xl,
                          const void* __restrict__ Dp)
{
    const int isbf = sniff_bf(Dp);
    const int gid = blockIdx.x * 256 + threadIdx.x;   // (NTOK/4)*(D_INNER/4)
    const int dq  = gid & (D_INNER / 4 - 1);          // channel quad 0..511
    const int tg  = gid >> 9;                         // token group 0..1023
    const int d0  = dq * 4;
    const int tok0 = tg * 4;
    const int l0  = tok0 & (SEQLEN - 1);              // position within sequence

    float w[4][4], bias[4];
#pragma unroll
    for (int dd = 0; dd < 4; dd++) {
        bias[dd] = ldF(conv_b, d0 + dd, isbf);
#pragma unroll
        for (int j = 0; j < 4; j++) w[dd][j] = ldF(conv_w, (d0 + dd) * 4 + j, isbf);
    }

    float4 x[7];
    const float* rowp = xz + (size_t)tok0 * (2 * D_INNER) + d0;
#pragma unroll
    for (int k = 0; k < 7; k++) {
        const int off = k - 3;
        if (l0 + off >= 0)
            x[k] = *(const float4*)(rowp + (ptrdiff_t)off * (2 * D_INNER));
        else
            x[k] = (float4){0.f, 0.f, 0.f, 0.f};
    }

#pragma unroll
    for (int tn = 0; tn < 4; tn++) {
        float a0 = bias[0], a1 = bias[1], a2 = bias[2], a3 = bias[3];
#pragma unroll
        for (int j = 0; j < 4; j++) {
            const float4 v = x[tn + j];
            a0 = fmaf(v.x, w[0][j], a0);
            a1 = fmaf(v.y, w[1][j], a1);
            a2 = fmaf(v.z, w[2][j], a2);
            a3 = fmaf(v.w, w[3][j], a3);
        }
        float4 o;
        o.x = a0 / (1.f + __expf(-a0));
        o.y = a1 / (1.f + __expf(-a1));
        o.z = a2 / (1.f + __expf(-a2));
        o.w = a3 / (1.f + __expf(-a3));
        *(float4*)&xl[(size_t)(tok0 + tn) * D_INNER + d0] = o;
    }
}

// ---------------------------------------------------------------------------
// Scan helpers (r19-verified): dA[n] = exp(dv*An[n]); power chain when
// An[n] ~= (n+1)*An[0] (runtime-verified).
// ---------------------------------------------------------------------------
__device__ __forceinline__ void mk_dA(float dv, const float An[16], int pw, float* dA)
{
    if (pw) {
        const float E = __expf(dv * An[0]);
        dA[0] = E;
        const float E2 = E * E;          dA[1] = E2;
        const float E4 = E2 * E2;        dA[3] = E4;
        const float E8 = E4 * E4;        dA[7] = E8;
        dA[2]  = E2 * E;
        dA[4]  = E4 * E;   dA[5]  = E4 * E2;  dA[6]  = dA[5] * E;
        dA[8]  = E8 * E;   dA[9]  = E8 * E2;  dA[10] = dA[9] * E;
        dA[11] = E8 * E4;  dA[12] = dA[11] * E;
        dA[13] = dA[11] * E2; dA[14] = dA[13] * E; dA[15] = E8 * E8;
    } else {
#pragma unroll
        for (int n = 0; n < 16; n++) dA[n] = __expf(dv * An[n]);
    }
}

__device__ __forceinline__ int chk_pw(const float An[16])
{
    int pw = 1;
#pragma unroll
    for (int n = 1; n < 16; n++)
        pw = pw && (fabsf(An[n] - (float)(n + 1) * An[0]) <= 3e-4f * (float)(n + 1));
    return pw;
}

__device__ __forceinline__ void scan_step(float h[16], float dv, float uv,
                                          const float Bv[16], const float An[16], int pw)
{
    float dA[16]; mk_dA(dv, An, pw, dA);
    const float du = dv * uv;
#pragma unroll
    for (int n = 0; n < 16; n++) h[n] = fmaf(dA[n], h[n], du * Bv[n]);
}

__device__ __forceinline__ float scan_step_y(float h[16], float dv, float uv,
                                             const float Bv[16], const float Cv[16],
                                             const float An[16], int pw, float Dd)
{
    float dA[16]; mk_dA(dv, An, pw, dA);
    const float du = dv * uv;
    float s[16];
#pragma unroll
    for (int n = 0; n < 16; n++) {
        h[n] = fmaf(dA[n], h[n], du * Bv[n]);
        s[n] = h[n] * Cv[n];
    }
#pragma unroll
    for (int n = 0; n < 8; n++) s[n] += s[n + 8];
#pragma unroll
    for (int n = 0; n < 4; n++) s[n] += s[n + 4];
    s[0] += s[2]; s[1] += s[3];
    return s[0] + s[1] + uv * Dd;
}

// ---------------------------------------------------------------------------
// Scan phase 1: per-chunk local scan (h0=0) -> S[b,c,n,d], sumD[b,c,d].
// ---------------------------------------------------------------------------
__launch_bounds__(256)
__global__ void scan_chunk(const float* __restrict__ dlt,
                           const float* __restrict__ xl,
                           const float* __restrict__ xdbl,
                           const void* __restrict__ A_log,
                           float* __restrict__ S,
                           float* __restrict__ sumD,
                           const void* __restrict__ Dp)
{
    const int isbf = sniff_bf(Dp);
    const int t  = threadIdx.x;
    const int dg = blockIdx.x & 7;
    const int c  = (blockIdx.x >> 3) & (NCH - 1);
    const int b  = blockIdx.x >> 9;
    const int d  = dg * 256 + t;

    float An[16], h[16];
#pragma unroll
    for (int n = 0; n < 16; n++) {
        An[n] = -expf(ldF(A_log, d * 16 + n, isbf));
        h[n] = 0.f;
    }
    const int pw = chk_pw(An);
    float sd = 0.f;
    const size_t r0 = (size_t)b * SEQLEN + c * LC;

    float dv0 = dlt[r0 * D_INNER + d];
    float uv0 = xl [r0 * D_INNER + d];
    float Bv0[16]; ld16f(&xdbl[r0 * 96 + 64], Bv0);

    for (int i = 0; i < LC; i += 2) {
        const size_t r1 = r0 + i + 1;
        float dv1 = dlt[r1 * D_INNER + d];
        float uv1 = xl [r1 * D_INNER + d];
        float Bv1[16]; ld16f(&xdbl[r1 * 96 + 64], Bv1);

        scan_step(h, dv0, uv0, Bv0, An, pw);
        sd += dv0;

        const size_t r2 = r0 + ((i + 2 < LC) ? (i + 2) : (i + 1));  // clamp
        dv0 = dlt[r2 * D_INNER + d];
        uv0 = xl [r2 * D_INNER + d];
        ld16f(&xdbl[r2 * 96 + 64], Bv0);

        scan_step(h, dv1, uv1, Bv1, An, pw);
        sd += dv1;
    }

    const size_t base = (((size_t)b * NCH + c) * 16) * D_INNER + d;
#pragma unroll
    for (int n = 0; n < 16; n++) S[base + (size_t)n * D_INNER] = h[n];
    sumD[((size_t)b * NCH + c) * D_INNER + d] = sd;
}

// ---------------------------------------------------------------------------
// Scan phase 2: combine chunk states; S rewritten with chunk-START state H0.
// ---------------------------------------------------------------------------
__launch_bounds__(256)
__global__ void scan_combine(float* __restrict__ S,
                             const float* __restrict__ sumD,
                             const void* __restrict__ A_log,
                             const void* __restrict__ Dp)
{
    const int isbf = sniff_bf(Dp);
    const int g = blockIdx.x * 256 + threadIdx.x;
    const int d = g & (D_INNER - 1);
    const int n = (g >> 11) & 15;
    const int b = g >> 15;
    const float An = -expf(ldF(A_log, d * 16 + n, isbf));

    float hs = 0.f;
    float Sc = S[(((size_t)b * NCH + 0) * 16 + n) * D_INNER + d];
    float sd = sumD[((size_t)b * NCH + 0) * D_INNER + d];
    for (int c = 0; c < NCH; c++) {
        const int cn = (c + 1 < NCH) ? c + 1 : c;
        const float Scn = S[(((size_t)b * NCH + cn) * 16 + n) * D_INNER + d];
        const float sdn = sumD[((size_t)b * NCH + cn) * D_INNER + d];
        S[(((size_t)b * NCH + c) * 16 + n) * D_INNER + d] = hs;
        hs = fmaf(__expf(An * sd), hs, Sc);
        Sc = Scn; sd = sdn;
    }
}

// ---------------------------------------------------------------------------
// Scan phase 3: seeded re-scan; y = sum_n h*C; D-skip + silu(z) gate -> bf16 yg.
// ---------------------------------------------------------------------------
__launch_bounds__(256)
__global__ void scan_apply(const float* __restrict__ dlt,
                           const float* __restrict__ xl,
                           const float* __restrict__ xdbl,
                           const float* __restrict__ xz,
                           const void* __restrict__ A_log,
                           const void* __restrict__ Dp,
                           const float* __restrict__ S,   // holds H0
                           unsigned short* __restrict__ yg)
{
    const int isbf = sniff_bf(Dp);
    const int t  = threadIdx.x;
    const int dg = blockIdx.x & 7;
    const int c  = (blockIdx.x >> 3) & (NCH - 1);
    const int b  = blockIdx.x >> 9;
    const int d  = dg * 256 + t;

    float An[16], h[16];
    const size_t base = (((size_t)b * NCH + c) * 16) * D_INNER + d;
#pragma unroll
    for (int n = 0; n < 16; n++) {
        An[n] = -expf(ldF(A_log, d * 16 + n, isbf));
        h[n] = S[base + (size_t)n * D_INNER];
    }
    const int pw = chk_pw(An);
    const float Dd = ldF(Dp, d, isbf);
    const size_t r0 = (size_t)b * SEQLEN + c * LC;

    float dv0 = dlt[r0 * D_INNER + d];
    float uv0 = xl [r0 * D_INNER + d];
    float zv0 = xz [r0 * (2 * D_INNER) + D_INNER + d];
    float Bv0[16], Cv0[16];
    ld16f(&xdbl[r0 * 96 + 64], Bv0);
    ld16f(&xdbl[r0 * 96 + 80], Cv0);

    for (int i = 0; i < LC; i += 2) {
        const size_t ra = r0 + i + 1;
        float dv1 = dlt[ra * D_INNER + d];
        float uv1 = xl [ra * D_INNER + d];
        float zv1 = xz [ra * (2 * D_INNER) + D_INNER + d];
        float Bv1[16], Cv1[16];
        ld16f(&xdbl[ra * 96 + 64], Bv1);
        ld16f(&xdbl[ra * 96 + 80], Cv1);

        {
            const float yv = scan_step_y(h, dv0, uv0, Bv0, Cv0, An, pw, Dd);
            yg[(r0 + i) * D_INNER + d] = f2bf(yv * (zv0 / (1.f + __expf(-zv0))));
        }

        const size_t rb = r0 + ((i + 2 < LC) ? (i + 2) : (i + 1));  // clamp
        dv0 = dlt[rb * D_INNER + d];
        uv0 = xl [rb * D_INNER + d];
        zv0 = xz [rb * (2 * D_INNER) + D_INNER + d];
        ld16f(&xdbl[rb * 96 + 64], Bv0);
        ld16f(&xdbl[rb * 96 + 80], Cv0);

        {
            const float yv = scan_step_y(h, dv1, uv1, Bv1, Cv1, An, pw, Dd);
            yg[ra * D_INNER + d] = f2bf(yv * (zv1 / (1.f + __expf(-zv1))));
        }
    }
}

// ---------------------------------------------------------------------------
extern "C" void kernel_launch(void* const* d_in, const int* in_sizes, int n_in,
                              void* d_out, int out_size, void* d_ws, size_t ws_size,
                              hipStream_t stream)
{
    const void* hidden     = d_in[0]; // f32
    const void* in_proj_w  = d_in[1];
    const void* conv_w     = d_in[2];
    const void* conv_b     = d_in[3];
    const void* x_proj_w   = d_in[4];
    const void* dt_proj_w  = d_in[5];
    const void* dt_proj_b  = d_in[6];
    const void* A_log      = d_in[7];
    const void* Dp         = d_in[8];
    const void* out_proj_w = d_in[9];

    char* ws = (char*)d_ws;
    float*          xz   = (float*)(ws);                        // [4096,4096]  64 MB
    float*          xl   = (float*)(ws + 67108864ull);          // [4096,2048]  32 MB
    float*          xdbl = (float*)(ws + 100663296ull);         // [4096,96]   1.5 MB
    float*          dlt  = (float*)(ws + 102236160ull);         // [4096,2048]  32 MB (step 4)
    unsigned short* yg   = (unsigned short*)(ws + 135790592ull);// [4096,2048] bf16 16 MB
    unsigned short* opwB = (unsigned short*)(ws + 152567808ull);// out_proj_w bf16 4 MB
    unsigned short* xdt  = (unsigned short*)(ws + 156762112ull);// [4096,64] bf16 512 KB (hole)
    unsigned short* dtwB = (unsigned short*)(ws + 157286400ull);// [2048,64] bf16 256 KB (hole)
    float*          S    = (float*)(ws + 169345280ull);         // 16 MB
    float*          sumD = (float*)(ws + 186122496ull);         // 1 MB
    int*            dmap = (int*)  (ws + 187171072ull);         // 256 B probe LUT
    // transient occupants of the dlt region (dead before dt-GEMM writes dlt):
    unsigned short* hidB  = (unsigned short*)(ws + 102236160ull);              // 8 MB
    unsigned short* ipwB  = (unsigned short*)(ws + 102236160ull + 8388608ull); // 8 MB
    float*          xpart = (float*)(ws + 102236160ull);        // [8,4096,96] 12.6 MB

    dim3 blk(256);

    // 0) f32 -> bf16 copies for MFMA operands + block-0 MFMA layout probe
    cvt_all<<<dim3(CVT_TOT / (256 * 8)), blk, 0, stream>>>(
        hidden, in_proj_w, out_proj_w, dt_proj_w, hidB, ipwB, opwB, dtwB, Dp, dmap);

    // 1) xz = hidden @ in_proj_w^T   [4096,4096]  (bf16 MFMA, 256^2 8-phase)
    hipFuncSetAttribute((const void*)gemm1_8ph,
                        hipFuncAttributeMaxDynamicSharedMemorySize, 131072);
    gemm1_8ph<<<dim3((NTOK / 256) * (2 * D_INNER / 256)), dim3(512), 131072, stream>>>(
        hidB, ipwB, xz, NTOK, 2 * D_INNER, D_MODEL, dmap);

    // 2) xl = silu(causal_conv1d(x) + conv_b)  (4-tok x 4-ch blocks)
    conv_silu<<<dim3((NTOK / 4) * (D_INNER / 4) / 256), blk, 0, stream>>>(
        xz, conv_w, conv_b, xl, Dp);

    // 3) xdbl = xl @ x_proj_w^T  via split-K  (+ fused bf16 xdt pack)
    xproj_splitk<<<dim3(2, 64, XKS), blk, 0, stream>>>(
        xl, (const float*)x_proj_w, xpart);
    xproj_reduce<<<dim3(NTOK * XNC / 256), blk, 0, stream>>>(xpart, xdbl, xdt);

    // 4) delta = softplus(dt @ dt_proj_w^T + dt_proj_b)  (single-stage K=64)
    gemm_dt<<<dim3((NTOK / 128) * (D_INNER / 128)), blk, 0, stream>>>(
        xdt, dtwB, dlt, dmap, dt_proj_b, Dp);

    // 5) chunked parallel scan + D-skip + silu(z) gate -> yg (bf16)
    scan_chunk<<<dim3(BATCH * NCH * (D_INNER / 256)), blk, 0, stream>>>(
        dlt, xl, xdbl, A_log, S, sumD, Dp);
    scan_combine<<<dim3(BATCH * 16 * D_INNER / 256), blk, 0, stream>>>(
        S, sumD, A_log, Dp);
    scan_apply<<<dim3(BATCH * NCH * (D_INNER / 256)), blk, 0, stream>>>(
        dlt, xl, xdbl, xz, A_log, Dp, S, yg);

    // 6) out = yg @ out_proj_w^T -> f32 d_out  (2-phase counted pipeline)
    gemm_op_2ph<<<dim3((NTOK / 128) * (D_MODEL / 64)), blk, 0, stream>>>(
        yg, opwB, (float*)d_out, dmap);
}

// Round 10
// 291.467 us; speedup vs baseline: 1.1554x; 1.0704x over previous
//
#include <hip/hip_runtime.h>

#define D_MODEL 1024
#define D_STATE 16
#define D_CONV  4
#define D_INNER 2048
#define DT_RANK 64
#define BATCH   2
#define SEQLEN  2048
#define NTOK    (BATCH * SEQLEN)   // 4096
#define NCH     64                 // scan chunks
#define LC      (SEQLEN / NCH)     // 32 steps per chunk
#define XKS     8                  // x_proj split-K factor
#define XNC     96                 // dt_rank + 2*d_state

// FACTS (r2-r12): inputs f32; d_out read as f32; bf16 internal copies for MFMA;
// async global_load_lds verified (r9); out_proj split-K regressed (r10); ws peak
// <= 187,171,328 B (r11 abort); dt_proj MFMA verified (r12). r13: out_proj BN=64
// + M-major. r14: in_proj 256^2/BK=64 8-phase — win. r15: scan power-chain —
// win. r16: conv 4x4 blocks — win. r17: out_proj 2-phase counted pipeline — win.
// r18 REGRESSED (conv fused into gemm1: spills + barrier skew). r19: gemm_dt
// single-stage + gate __expf — win. r20/r21 REGRESSED (scan n-split: scan is
// LOAD-ISSUE-bound, not VALU-chain-bound). r22/r9: revert — 312.0 best.
// r23 (this round): xproj_splitk (last f32 vector GEMM, ~1.6 GFLOP + 64 MB
// double-read of xl) replaced by bf16 MFMA split-K gemm_xp (BM=128 BN=96 BK=64,
// 2-phase counted pipeline, 256 blocks); conv emits bf16 xlB; cvt adds xpwB.
// xlB+xpart alias the dlt region sequentially. Precision: +1 bf16 rounding on
// B/C inputs — revert to f32 splitk if harness fails.

// ---------- bf16 helpers ----------
__device__ __forceinline__ float bf2f(unsigned short v) {
    union { unsigned int u; float f; } c; c.u = ((unsigned int)v) << 16; return c.f;
}
__device__ __forceinline__ unsigned short f2bf(float f) {
    union { unsigned int u; float f; } c; c.f = f;
    unsigned int r = c.u + 0x7FFF + ((c.u >> 16) & 1);   // RNE
    return (unsigned short)(r >> 16);
}

__device__ __forceinline__ int sniff_bf(const void* Dp) {
    return (((const unsigned int*)Dp)[0] == 0x3F803F80u) ? 1 : 0;
}

__device__ __forceinline__ float ldF(const void* p, size_t idx, int isbf) {
    return isbf ? bf2f(((const unsigned short*)p)[idx]) : ((const float*)p)[idx];
}
__device__ __forceinline__ void ld16f(const float* p, float* o) {
#pragma unroll
    for (int q = 0; q < 4; q++) {
        float4 v = *(const float4*)(p + 4 * q);
        o[4 * q + 0] = v.x; o[4 * q + 1] = v.y; o[4 * q + 2] = v.z; o[4 * q + 3] = v.w;
    }
}

typedef __attribute__((ext_vector_type(8))) __bf16 bf16x8;
typedef __attribute__((ext_vector_type(4))) float  f32x4;

// ---------------------------------------------------------------------------
// MFMA layout probe (r8-verified), block-0 section of cvt_all.
// dmap[lane*4+r] = row | col<<4 in loader coords.
// ---------------------------------------------------------------------------
__device__ void probe_dmap_block(int t, int* __restrict__ dmap)
{
    __shared__ alignas(16) unsigned short PAs[16 * 32];
    __shared__ alignas(16) unsigned short PBs[16 * 32];
    const int q = (t & 63) >> 4, l15 = t & 15;

    if (t < 64)
        for (int idx = t; idx < 512; idx += 64) {
            PAs[idx] = f2bf((float)(idx >> 5));
            PBs[idx] = f2bf(0.03125f);
        }
    __syncthreads();
    f32x4 acc1 = {0.f, 0.f, 0.f, 0.f};
    if (t < 64) {
        bf16x8 a1 = *(const bf16x8*)&PAs[l15 * 32 + q * 8];
        bf16x8 b1 = *(const bf16x8*)&PBs[l15 * 32 + q * 8];
        acc1 = __builtin_amdgcn_mfma_f32_16x16x32_bf16(a1, b1, acc1, 0, 0, 0);
    }
    __syncthreads();
    if (t < 64)
        for (int idx = t; idx < 512; idx += 64) {
            PAs[idx] = f2bf(0.03125f);
            PBs[idx] = f2bf((float)(idx >> 5));
        }
    __syncthreads();
    if (t < 64) {
        bf16x8 a2 = *(const bf16x8*)&PAs[l15 * 32 + q * 8];
        bf16x8 b2 = *(const bf16x8*)&PBs[l15 * 32 + q * 8];
        f32x4 acc2 = {0.f, 0.f, 0.f, 0.f};
        acc2 = __builtin_amdgcn_mfma_f32_16x16x32_bf16(a2, b2, acc2, 0, 0, 0);
#pragma unroll
        for (int r = 0; r < 4; r++) {
            int ma = (int)(acc1[r] + 0.5f);
            int nb = (int)(acc2[r] + 0.5f);
            if (ma < 0 || ma > 15 || nb < 0 || nb > 15) { ma = q * 4 + r; nb = l15; }
            dmap[t * 4 + r] = ma | (nb << 4);
        }
    }
}

// ---------------------------------------------------------------------------
// Fused bf16 conversion for the 5 MFMA operand copies (8 elems/thread)
// + block-0 MFMA layout probe.
// ---------------------------------------------------------------------------
#define CVT_N0 (NTOK * D_MODEL)        // hidden   4,194,304
#define CVT_N1 (2 * D_INNER * D_MODEL) // in_proj  4,194,304
#define CVT_N2 (D_MODEL * D_INNER)     // out_proj 2,097,152
#define CVT_N3 (D_INNER * DT_RANK)     // dt_proj    131,072
#define CVT_N4 (XNC * D_INNER)         // x_proj     196,608
#define CVT_TOT (CVT_N0 + CVT_N1 + CVT_N2 + CVT_N3 + CVT_N4)

__device__ __forceinline__ void cvt8(const void* in, unsigned short* out,
                                     size_t e0, int isbf)
{
    if (isbf) {
        *(uint4*)(out + e0) = *(const uint4*)((const unsigned short*)in + e0);
    } else {
        const float* f = (const float*)in + e0;
        float4 a = *(const float4*)f;
        float4 b = *(const float4*)(f + 4);
        ushort4 o0 = { f2bf(a.x), f2bf(a.y), f2bf(a.z), f2bf(a.w) };
        ushort4 o1 = { f2bf(b.x), f2bf(b.y), f2bf(b.z), f2bf(b.w) };
        *(ushort4*)(out + e0)     = o0;
        *(ushort4*)(out + e0 + 4) = o1;
    }
}

__launch_bounds__(256)
__global__ void cvt_all(const void* __restrict__ hid, const void* __restrict__ ipw,
                        const void* __restrict__ opw, const void* __restrict__ dtw,
                        const void* __restrict__ xpw,
                        unsigned short* __restrict__ hidB, unsigned short* __restrict__ ipwB,
                        unsigned short* __restrict__ opwB, unsigned short* __restrict__ dtwB,
                        unsigned short* __restrict__ xpwB,
                        const void* __restrict__ Dp, int* __restrict__ dmap)
{
    if (blockIdx.x == 0) probe_dmap_block(threadIdx.x, dmap);

    const int isbf = sniff_bf(Dp);
    size_t e = ((size_t)blockIdx.x * 256 + threadIdx.x) * 8;
    if (e < CVT_N0) { cvt8(hid, hidB, e, isbf); return; }
    e -= CVT_N0;
    if (e < CVT_N1) { cvt8(ipw, ipwB, e, isbf); return; }
    e -= CVT_N1;
    if (e < CVT_N2) { cvt8(opw, opwB, e, isbf); return; }
    e -= CVT_N2;
    if (e < CVT_N3) { cvt8(dtw, dtwB, e, isbf); return; }
    e -= CVT_N3;
    if (e < CVT_N4) { cvt8(xpw, xpwB, e, isbf); }
}

// ---------------------------------------------------------------------------
__device__ __forceinline__ void gl2lds16(const void* g, void* l) {
    __builtin_amdgcn_global_load_lds(
        (const __attribute__((address_space(1))) unsigned int*)g,
        (__attribute__((address_space(3))) unsigned int*)l,
        16, 0, 0);
}

// ===========================================================================
// in_proj GEMM: 256x256 tile, BK=64, 8 waves, 8-phase schedule (r14-verified).
// ===========================================================================
__device__ __forceinline__ void stage_half(const unsigned short* __restrict__ G,
                                           int grow0, int K, int k0,
                                           unsigned short* ldsAB, int half, int t)
{
    const int r8  = t >> 3;                 // 0..63: row within 64-row group
    const int c8  = t & 7;                  // physical 16B slot
    const int swz = (c8 ^ (r8 & 7)) << 3;   // logical col in shorts
#pragma unroll
    for (int j = 0; j < 2; j++) {
        const int row = half * 128 + j * 64 + r8;
        gl2lds16(&G[(size_t)(grow0 + row) * K + k0 + swz],
                 &ldsAB[row * 64 + c8 * 8]);
    }
}

__device__ __forceinline__ bf16x8 ldsfrag(const unsigned short* p, int row, int slot) {
    return *(const bf16x8*)&p[row * 64 + ((slot ^ (row & 7)) << 3)];
}

__launch_bounds__(512)
__global__ void gemm1_8ph(const unsigned short* __restrict__ A,
                          const unsigned short* __restrict__ B,
                          float* __restrict__ C,
                          int M, int N, int K,
                          const int* __restrict__ dmap)
{
    extern __shared__ __align__(16) unsigned short lds[];
    unsigned short* A0l = lds;              // buf0 A [256][64]
    unsigned short* B0l = lds + 16384;      // buf0 B
    unsigned short* A1l = lds + 32768;      // buf1 A
    unsigned short* B1l = lds + 49152;      // buf1 B

    const int t    = threadIdx.x;
    const int lane = t & 63;
    const int w    = t >> 6;
    const int wm   = (w >> 2) * 128, wn = (w & 3) * 64;
    const int q    = lane >> 4, l15 = lane & 15;

    const int nbn  = N >> 8;
    const int nwg  = (M >> 8) * nbn;        // 256 here: % 8 == 0 -> bijective
    const int orig = blockIdx.x;
    const int wg   = (orig & 7) * (nwg >> 3) + (orig >> 3);
    const int bm   = wg / nbn, bn = wg % nbn;
    const int m0   = bm << 8, n0 = bn << 8;
    const int NT   = K >> 6;

    int mp[4];
#pragma unroll
    for (int r = 0; r < 4; r++) mp[r] = dmap[lane * 4 + r];

    f32x4 acc[8][4];
#pragma unroll
    for (int i = 0; i < 8; i++)
#pragma unroll
        for (int j = 0; j < 4; j++) acc[i][j] = (f32x4){0.f, 0.f, 0.f, 0.f};

    // ---- prologue: tile0 {B,A}, tile1 {B}; wait oldest 8 (= tile0 complete)
    stage_half(B, n0, K, 0, B0l, 0, t);
    stage_half(B, n0, K, 0, B0l, 1, t);
    stage_half(A, m0, K, 0, A0l, 0, t);
    stage_half(A, m0, K, 0, A0l, 1, t);
    {
        const int k1 = (NT > 1 ? 64 : 0);
        stage_half(B, n0, K, k1, B1l, 0, t);
        stage_half(B, n0, K, k1, B1l, 1, t);
    }
    asm volatile("s_waitcnt vmcnt(4)" ::: "memory");
    __builtin_amdgcn_s_barrier();

#pragma unroll 2
    for (int tt = 0; tt < NT; ++tt) {
        const int p = tt & 1;
        const unsigned short* Ac = p ? A1l : A0l;
        const unsigned short* Bc = p ? B1l : B0l;
        unsigned short* Anx = p ? A0l : A1l;   // tile tt+1 A (other buf)
        unsigned short* Bnx = p ? B1l : B0l;   // tile tt+2 B (same buf, dead after ph1)
        const int kA = (tt + 1 < NT ? tt + 1 : 0) << 6;
        const int kB = (tt + 2 < NT ? tt + 2 : 0) << 6;

        bf16x8 af[4][2], b0r[2][2], b1r[2][2];

        // ---------------- phase 0: quadrant (mh0, nh0)
#pragma unroll
        for (int i = 0; i < 4; i++)
#pragma unroll
            for (int ks = 0; ks < 2; ks++)
                af[i][ks] = ldsfrag(Ac, wm + i * 16 + l15, ks * 4 + q);
#pragma unroll
        for (int j = 0; j < 2; j++)
#pragma unroll
            for (int ks = 0; ks < 2; ks++)
                b0r[j][ks] = ldsfrag(Bc, wn + j * 16 + l15, ks * 4 + q);
        stage_half(A, m0, K, kA, Anx, 0, t);
        asm volatile("" ::: "memory");
        __builtin_amdgcn_s_barrier();
        __builtin_amdgcn_s_setprio(1);
#pragma unroll
        for (int i = 0; i < 4; i++)
#pragma unroll
            for (int j = 0; j < 2; j++)
#pragma unroll
                for (int ks = 0; ks < 2; ks++)
                    acc[i][j] = __builtin_amdgcn_mfma_f32_16x16x32_bf16(
                        af[i][ks], b0r[j][ks], acc[i][j], 0, 0, 0);
        __builtin_amdgcn_s_setprio(0);
        asm volatile("" ::: "memory");
        __builtin_amdgcn_s_barrier();

        // ---------------- phase 1: quadrant (mh0, nh1)
#pragma unroll
        for (int j = 0; j < 2; j++)
#pragma unroll
            for (int ks = 0; ks < 2; ks++)
                b1r[j][ks] = ldsfrag(Bc, wn + 32 + j * 16 + l15, ks * 4 + q);
        stage_half(A, m0, K, kA, Anx, 1, t);
        asm volatile("" ::: "memory");
        __builtin_amdgcn_s_barrier();
        __builtin_amdgcn_s_setprio(1);
#pragma unroll
        for (int i = 0; i < 4; i++)
#pragma unroll
            for (int j = 0; j < 2; j++)
#pragma unroll
                for (int ks = 0; ks < 2; ks++)
                    acc[i][2 + j] = __builtin_amdgcn_mfma_f32_16x16x32_bf16(
                        af[i][ks], b1r[j][ks], acc[i][2 + j], 0, 0, 0);
        __builtin_amdgcn_s_setprio(0);
        asm volatile("" ::: "memory");
        __builtin_amdgcn_s_barrier();

        // ---------------- phase 2: quadrant (mh1, nh1)
#pragma unroll
        for (int i = 0; i < 4; i++)
#pragma unroll
            for (int ks = 0; ks < 2; ks++)
                af[i][ks] = ldsfrag(Ac, wm + 64 + i * 16 + l15, ks * 4 + q);
        stage_half(B, n0, K, kB, Bnx, 0, t);
        asm volatile("" ::: "memory");
        __builtin_amdgcn_s_barrier();
        __builtin_amdgcn_s_setprio(1);
#pragma unroll
        for (int i = 0; i < 4; i++)
#pragma unroll
            for (int j = 0; j < 2; j++)
#pragma unroll
                for (int ks = 0; ks < 2; ks++)
                    acc[4 + i][2 + j] = __builtin_amdgcn_mfma_f32_16x16x32_bf16(
                        af[i][ks], b1r[j][ks], acc[4 + i][2 + j], 0, 0, 0);
        __builtin_amdgcn_s_setprio(0);
        asm volatile("" ::: "memory");
        __builtin_amdgcn_s_barrier();

        // ---------------- phase 3: quadrant (mh1, nh0)
        stage_half(B, n0, K, kB, Bnx, 1, t);
        asm volatile("" ::: "memory");
        __builtin_amdgcn_s_barrier();
        __builtin_amdgcn_s_setprio(1);
#pragma unroll
        for (int i = 0; i < 4; i++)
#pragma unroll
            for (int j = 0; j < 2; j++)
#pragma unroll
                for (int ks = 0; ks < 2; ks++)
                    acc[4 + i][j] = __builtin_amdgcn_mfma_f32_16x16x32_bf16(
                        af[i][ks], b0r[j][ks], acc[4 + i][j], 0, 0, 0);
        __builtin_amdgcn_s_setprio(0);
        asm volatile("s_waitcnt vmcnt(4)" ::: "memory");
        __builtin_amdgcn_s_barrier();
    }

    // ---- epilogue
#pragma unroll
    for (int i = 0; i < 8; i++) {
#pragma unroll
        for (int r = 0; r < 4; r++) {
            const int mo = mp[r] & 15, no = mp[r] >> 4;
            const int m = m0 + wm + i * 16 + mo;
#pragma unroll
            for (int j = 0; j < 4; j++) {
                const int n = n0 + wn + j * 16 + no;
                C[(size_t)m * N + n] = acc[i][j][r];
            }
        }
    }
}

// ===========================================================================
// out_proj GEMM: 128x64 tile, BK=64, 4 waves, 2-phase counted pipeline
// (r17-verified). T2 XOR-swizzle. Grid 512 = 2 blocks/CU.
// ===========================================================================
__device__ __forceinline__ void stage_op(const unsigned short* __restrict__ A,
                                         const unsigned short* __restrict__ B,
                                         int m0, int n0, int K, int k0,
                                         unsigned short* Al, unsigned short* Bl, int t)
{
    const int r   = t >> 3;                 // 0..31
    const int c8  = t & 7;                  // physical 16B slot
    const int swz = (c8 ^ (r & 7)) << 3;    // logical col in shorts
#pragma unroll
    for (int j = 0; j < 4; j++) {           // A rows 0..127
        const int row = j * 32 + r;
        gl2lds16(&A[(size_t)(m0 + row) * K + k0 + swz], &Al[row * 64 + c8 * 8]);
    }
#pragma unroll
    for (int j = 0; j < 2; j++) {           // B rows 0..63
        const int row = j * 32 + r;
        gl2lds16(&B[(size_t)(n0 + row) * K + k0 + swz], &Bl[row * 64 + c8 * 8]);
    }
}

__launch_bounds__(256)
__global__ void gemm_op_2ph(const unsigned short* __restrict__ A,   // yg [4096][2048]
                            const unsigned short* __restrict__ B,   // opwB [1024][2048]
                            float* __restrict__ C,                  // [4096][1024]
                            const int* __restrict__ dmap)
{
    constexpr int M = NTOK, N = D_MODEL, K = D_INNER;
    constexpr int NT = K / 64;               // 32
    __shared__ alignas(16) unsigned short Al[2][128 * 64];  // 32 KB
    __shared__ alignas(16) unsigned short Bl[2][64 * 64];   // 16 KB

    const int t    = threadIdx.x;
    const int lane = t & 63;
    const int w    = t >> 6;
    const int wm   = (w >> 1) * 64, wn = (w & 1) * 32;
    const int q    = lane >> 4, l15 = lane & 15;

    const int nbn  = N / 64;                 // 16
    const int nwg  = (M / 128) * nbn;        // 512, % 8 == 0
    const int orig = blockIdx.x;
    const int wg   = (orig & 7) * (nwg >> 3) + (orig >> 3);
    const int bm   = wg / nbn, bn = wg % nbn;
    const int m0   = bm * 128, n0 = bn * 64;

    int mp[4];
#pragma unroll
    for (int r = 0; r < 4; r++) mp[r] = dmap[lane * 4 + r];

    f32x4 acc[4][2];
#pragma unroll
    for (int i = 0; i < 4; i++)
#pragma unroll
        for (int j = 0; j < 2; j++) acc[i][j] = (f32x4){0.f, 0.f, 0.f, 0.f};

    stage_op(A, B, m0, n0, K, 0, Al[0], Bl[0], t);
    asm volatile("s_waitcnt vmcnt(0)" ::: "memory");
    __builtin_amdgcn_s_barrier();

#pragma unroll 2
    for (int tt = 0; tt < NT - 1; ++tt) {
        const int cur = tt & 1;
        stage_op(A, B, m0, n0, K, (tt + 1) * 64, Al[cur ^ 1], Bl[cur ^ 1], t);

        bf16x8 af[4][2], bfr[2][2];
#pragma unroll
        for (int i = 0; i < 4; i++)
#pragma unroll
            for (int ks = 0; ks < 2; ks++)
                af[i][ks] = ldsfrag(Al[cur], wm + i * 16 + l15, ks * 4 + q);
#pragma unroll
        for (int j = 0; j < 2; j++)
#pragma unroll
            for (int ks = 0; ks < 2; ks++)
                bfr[j][ks] = ldsfrag(Bl[cur], wn + j * 16 + l15, ks * 4 + q);
        __builtin_amdgcn_s_setprio(1);
#pragma unroll
        for (int i = 0; i < 4; i++)
#pragma unroll
            for (int j = 0; j < 2; j++)
#pragma unroll
                for (int ks = 0; ks < 2; ks++)
                    acc[i][j] = __builtin_amdgcn_mfma_f32_16x16x32_bf16(
                        af[i][ks], bfr[j][ks], acc[i][j], 0, 0, 0);
        __builtin_amdgcn_s_setprio(0);
        asm volatile("s_waitcnt vmcnt(0)" ::: "memory");
        __builtin_amdgcn_s_barrier();
    }

    {
        const int cur = (NT - 1) & 1;
        bf16x8 af[4][2], bfr[2][2];
#pragma unroll
        for (int i = 0; i < 4; i++)
#pragma unroll
            for (int ks = 0; ks < 2; ks++)
                af[i][ks] = ldsfrag(Al[cur], wm + i * 16 + l15, ks * 4 + q);
#pragma unroll
        for (int j = 0; j < 2; j++)
#pragma unroll
            for (int ks = 0; ks < 2; ks++)
                bfr[j][ks] = ldsfrag(Bl[cur], wn + j * 16 + l15, ks * 4 + q);
#pragma unroll
        for (int i = 0; i < 4; i++)
#pragma unroll
            for (int j = 0; j < 2; j++)
#pragma unroll
                for (int ks = 0; ks < 2; ks++)
                    acc[i][j] = __builtin_amdgcn_mfma_f32_16x16x32_bf16(
                        af[i][ks], bfr[j][ks], acc[i][j], 0, 0, 0);
    }

#pragma unroll
    for (int i = 0; i < 4; i++) {
#pragma unroll
        for (int r = 0; r < 4; r++) {
            const int mo = mp[r] & 15, no = mp[r] >> 4;
            const int m = m0 + wm + i * 16 + mo;
#pragma unroll
            for (int j = 0; j < 2; j++) {
                const int n = n0 + wn + j * 16 + no;
                C[(size_t)m * N + n] = acc[i][j][r];
            }
        }
    }
}

// ===========================================================================
// x_proj GEMM (r23): part[z] = xlB[:, z*256:(z+1)*256] @ xpwB[:, same]^T
// BM=128 x BN=96 (6 n-frags), BK=64, 2-phase counted pipeline, grid 32x8.
// ===========================================================================
__launch_bounds__(256)
__global__ void gemm_xp(const unsigned short* __restrict__ A,   // xlB [4096][2048]
                        const unsigned short* __restrict__ B,   // xpwB [96][2048]
                        float* __restrict__ part,               // [XKS][4096][96]
                        const int* __restrict__ dmap)
{
    constexpr int K  = D_INNER;          // 2048
    constexpr int KC = K / XKS;          // 256 per split-K chunk
    constexpr int NT = KC / 64;          // 4
    __shared__ alignas(16) unsigned short Al[2][128 * 64];  // 32 KB
    __shared__ alignas(16) unsigned short Bl[2][96 * 64];   // 24 KB

    const int t    = threadIdx.x;
    const int lane = t & 63;
    const int w    = t >> 6;
    const int wm   = (w >> 1) * 64, wn = (w & 1) * 48;   // 2x2 waves: 64m x 48n
    const int q    = lane >> 4, l15 = lane & 15;

    const int m0   = blockIdx.x * 128;   // 0..31
    const int z    = blockIdx.y;         // 0..7
    const int koff = z * KC;

    int mp[4];
#pragma unroll
    for (int r = 0; r < 4; r++) mp[r] = dmap[lane * 4 + r];

    f32x4 acc[4][3];
#pragma unroll
    for (int i = 0; i < 4; i++)
#pragma unroll
        for (int j = 0; j < 3; j++) acc[i][j] = (f32x4){0.f, 0.f, 0.f, 0.f};

    auto stage_xp = [&](int k0, unsigned short* Ald, unsigned short* Bld) {
        const int r   = t >> 3;
        const int c8  = t & 7;
        const int swz = (c8 ^ (r & 7)) << 3;
#pragma unroll
        for (int j = 0; j < 4; j++) {        // A rows 0..127
            const int row = j * 32 + r;
            gl2lds16(&A[(size_t)(m0 + row) * K + koff + k0 + swz],
                     &Ald[row * 64 + c8 * 8]);
        }
#pragma unroll
        for (int j = 0; j < 3; j++) {        // B rows 0..95
            const int row = j * 32 + r;
            gl2lds16(&B[(size_t)row * K + koff + k0 + swz],
                     &Bld[row * 64 + c8 * 8]);
        }
    };

    stage_xp(0, Al[0], Bl[0]);
    asm volatile("s_waitcnt vmcnt(0)" ::: "memory");
    __builtin_amdgcn_s_barrier();

#pragma unroll
    for (int tt = 0; tt < NT - 1; ++tt) {
        const int cur = tt & 1;
        stage_xp((tt + 1) * 64, Al[cur ^ 1], Bl[cur ^ 1]);

        bf16x8 af[4][2], bfr[3][2];
#pragma unroll
        for (int i = 0; i < 4; i++)
#pragma unroll
            for (int ks = 0; ks < 2; ks++)
                af[i][ks] = ldsfrag(Al[cur], wm + i * 16 + l15, ks * 4 + q);
#pragma unroll
        for (int j = 0; j < 3; j++)
#pragma unroll
            for (int ks = 0; ks < 2; ks++)
                bfr[j][ks] = ldsfrag(Bl[cur], wn + j * 16 + l15, ks * 4 + q);
        __builtin_amdgcn_s_setprio(1);
#pragma unroll
        for (int i = 0; i < 4; i++)
#pragma unroll
            for (int j = 0; j < 3; j++)
#pragma unroll
                for (int ks = 0; ks < 2; ks++)
                    acc[i][j] = __builtin_amdgcn_mfma_f32_16x16x32_bf16(
                        af[i][ks], bfr[j][ks], acc[i][j], 0, 0, 0);
        __builtin_amdgcn_s_setprio(0);
        asm volatile("s_waitcnt vmcnt(0)" ::: "memory");
        __builtin_amdgcn_s_barrier();
    }

    {
        const int cur = (NT - 1) & 1;
        bf16x8 af[4][2], bfr[3][2];
#pragma unroll
        for (int i = 0; i < 4; i++)
#pragma unroll
            for (int ks = 0; ks < 2; ks++)
                af[i][ks] = ldsfrag(Al[cur], wm + i * 16 + l15, ks * 4 + q);
#pragma unroll
        for (int j = 0; j < 3; j++)
#pragma unroll
            for (int ks = 0; ks < 2; ks++)
                bfr[j][ks] = ldsfrag(Bl[cur], wn + j * 16 + l15, ks * 4 + q);
#pragma unroll
        for (int i = 0; i < 4; i++)
#pragma unroll
            for (int j = 0; j < 3; j++)
#pragma unroll
                for (int ks = 0; ks < 2; ks++)
                    acc[i][j] = __builtin_amdgcn_mfma_f32_16x16x32_bf16(
                        af[i][ks], bfr[j][ks], acc[i][j], 0, 0, 0);
    }

    float* out = part + (size_t)z * NTOK * XNC;
#pragma unroll
    for (int i = 0; i < 4; i++) {
#pragma unroll
        for (int r = 0; r < 4; r++) {
            const int mo = mp[r] & 15, no = mp[r] >> 4;
            const int m = m0 + wm + i * 16 + mo;
#pragma unroll
            for (int j = 0; j < 3; j++) {
                const int n = wn + j * 16 + no;   // < 96 always
                out[(size_t)m * XNC + n] = acc[i][j][r];
            }
        }
    }
}

// ===========================================================================
// dt_proj GEMM (K=64): 128x128 tile, single 32KB stage (r19-verified).
// ===========================================================================
__launch_bounds__(256)
__global__ void gemm_dt(const unsigned short* __restrict__ A,   // xdt [4096][64]
                        const unsigned short* __restrict__ B,   // dtwB [2048][64]
                        float* __restrict__ C,                  // dlt [4096][2048]
                        const int* __restrict__ dmap,
                        const void* __restrict__ bias,
                        const void* __restrict__ Dp)
{
    constexpr int M = NTOK, N = D_INNER, K = DT_RANK;   // 4096, 2048, 64
    __shared__ alignas(16) unsigned short Al[128 * 64]; // 16 KB
    __shared__ alignas(16) unsigned short Bl[128 * 64]; // 16 KB

    const int t    = threadIdx.x;
    const int lane = t & 63;
    const int w    = t >> 6;
    const int wm   = (w >> 1) * 64, wn = (w & 1) * 64;
    const int q    = lane >> 4, l15 = lane & 15;

    const int nbn  = N / 128;                // 16
    const int nwg  = (M / 128) * nbn;        // 512, % 8 == 0 -> bijective
    const int orig = blockIdx.x;
    const int wg   = (orig & 7) * (nwg >> 3) + (orig >> 3);
    const int bm   = wg / nbn, bn = wg % nbn;
    const int m0   = bm * 128, n0 = bn * 128;

    int mp[4];
#pragma unroll
    for (int r = 0; r < 4; r++) mp[r] = dmap[lane * 4 + r];

    {
        const int r   = t >> 3;              // 0..31
        const int c8  = t & 7;
        const int swz = (c8 ^ (r & 7)) << 3;
#pragma unroll
        for (int j = 0; j < 4; j++) {
            const int row = j * 32 + r;
            gl2lds16(&A[(size_t)(m0 + row) * K + swz], &Al[row * 64 + c8 * 8]);
            gl2lds16(&B[(size_t)(n0 + row) * K + swz], &Bl[row * 64 + c8 * 8]);
        }
    }
    asm volatile("s_waitcnt vmcnt(0)" ::: "memory");
    __builtin_amdgcn_s_barrier();

    f32x4 acc[4][4];
#pragma unroll
    for (int i = 0; i < 4; i++)
#pragma unroll
        for (int j = 0; j < 4; j++) acc[i][j] = (f32x4){0.f, 0.f, 0.f, 0.f};

    bf16x8 af[4][2], bfr[4][2];
#pragma unroll
    for (int i = 0; i < 4; i++)
#pragma unroll
        for (int ks = 0; ks < 2; ks++)
            af[i][ks] = ldsfrag(Al, wm + i * 16 + l15, ks * 4 + q);
#pragma unroll
    for (int j = 0; j < 4; j++)
#pragma unroll
        for (int ks = 0; ks < 2; ks++)
            bfr[j][ks] = ldsfrag(Bl, wn + j * 16 + l15, ks * 4 + q);
#pragma unroll
    for (int i = 0; i < 4; i++)
#pragma unroll
        for (int j = 0; j < 4; j++)
#pragma unroll
            for (int ks = 0; ks < 2; ks++)
                acc[i][j] = __builtin_amdgcn_mfma_f32_16x16x32_bf16(
                    af[i][ks], bfr[j][ks], acc[i][j], 0, 0, 0);

    const int isbf = sniff_bf(Dp);
#pragma unroll
    for (int i = 0; i < 4; i++) {
#pragma unroll
        for (int r = 0; r < 4; r++) {
            const int mo = mp[r] & 15, no = mp[r] >> 4;
            const int m = m0 + wm + i * 16 + mo;
#pragma unroll
            for (int j = 0; j < 4; j++) {
                const int n = n0 + wn + j * 16 + no;
                float v = acc[i][j][r] + ldF(bias, n, isbf);
                v = fmaxf(v, 0.f) + __logf(1.f + __expf(-fabsf(v)));   // softplus
                C[(size_t)m * N + n] = v;
            }
        }
    }
}

// reduce split-K parts -> xdbl; also emit bf16 xdt (cols 0..63) for dt-GEMM
__launch_bounds__(256)
__global__ void xproj_reduce(const float* __restrict__ part, float* __restrict__ xdbl,
                             unsigned short* __restrict__ xdt)
{
    const int idx = blockIdx.x * 256 + threadIdx.x;          // NTOK*XNC
    float s = 0.f;
#pragma unroll
    for (int z = 0; z < XKS; z++) s += part[(size_t)z * NTOK * XNC + idx];
    xdbl[idx] = s;
    const int m = idx / XNC;
    const int col = idx - m * XNC;
    if (col < 64) xdt[m * 64 + col] = f2bf(s);
}

// ---------------------------------------------------------------------------
// Depthwise causal conv1d (d_conv=4) + SiLU (r16-verified).
// r23: also emits bf16 xlB for the x_proj MFMA GEMM.
// ---------------------------------------------------------------------------
__launch_bounds__(256)
__global__ void conv_silu(const float* __restrict__ xz,
                          const void* __restrict__ conv_w,
                          const void* __restrict__ conv_b,
                          float* __restrict__ xl,
                          unsigned short* __restrict__ xlB,
                          const void* __restrict__ Dp)
{
    const int isbf = sniff_bf(Dp);
    const int gid = blockIdx.x * 256 + threadIdx.x;   // (NTOK/4)*(D_INNER/4)
    const int dq  = gid & (D_INNER / 4 - 1);          // channel quad 0..511
    const int tg  = gid >> 9;                         // token group 0..1023
    const int d0  = dq * 4;
    const int tok0 = tg * 4;
    const int l0  = tok0 & (SEQLEN - 1);              // position within sequence

    float w[4][4], bias[4];
#pragma unroll
    for (int dd = 0; dd < 4; dd++) {
        bias[dd] = ldF(conv_b, d0 + dd, isbf);
#pragma unroll
        for (int j = 0; j < 4; j++) w[dd][j] = ldF(conv_w, (d0 + dd) * 4 + j, isbf);
    }

    float4 x[7];
    const float* rowp = xz + (size_t)tok0 * (2 * D_INNER) + d0;
#pragma unroll
    for (int k = 0; k < 7; k++) {
        const int off = k - 3;
        if (l0 + off >= 0)
            x[k] = *(const float4*)(rowp + (ptrdiff_t)off * (2 * D_INNER));
        else
            x[k] = (float4){0.f, 0.f, 0.f, 0.f};
    }

#pragma unroll
    for (int tn = 0; tn < 4; tn++) {
        float a0 = bias[0], a1 = bias[1], a2 = bias[2], a3 = bias[3];
#pragma unroll
        for (int j = 0; j < 4; j++) {
            const float4 v = x[tn + j];
            a0 = fmaf(v.x, w[0][j], a0);
            a1 = fmaf(v.y, w[1][j], a1);
            a2 = fmaf(v.z, w[2][j], a2);
            a3 = fmaf(v.w, w[3][j], a3);
        }
        float4 o;
        o.x = a0 / (1.f + __expf(-a0));
        o.y = a1 / (1.f + __expf(-a1));
        o.z = a2 / (1.f + __expf(-a2));
        o.w = a3 / (1.f + __expf(-a3));
        *(float4*)&xl[(size_t)(tok0 + tn) * D_INNER + d0] = o;
        ushort4 ob = { f2bf(o.x), f2bf(o.y), f2bf(o.z), f2bf(o.w) };
        *(ushort4*)&xlB[(size_t)(tok0 + tn) * D_INNER + d0] = ob;
    }
}

// ---------------------------------------------------------------------------
// Scan helpers (r19-verified): dA[n] = exp(dv*An[n]); power chain when
// An[n] ~= (n+1)*An[0] (runtime-verified).
// ---------------------------------------------------------------------------
__device__ __forceinline__ void mk_dA(float dv, const float An[16], int pw, float* dA)
{
    if (pw) {
        const float E = __expf(dv * An[0]);
        dA[0] = E;
        const float E2 = E * E;          dA[1] = E2;
        const float E4 = E2 * E2;        dA[3] = E4;
        const float E8 = E4 * E4;        dA[7] = E8;
        dA[2]  = E2 * E;
        dA[4]  = E4 * E;   dA[5]  = E4 * E2;  dA[6]  = dA[5] * E;
        dA[8]  = E8 * E;   dA[9]  = E8 * E2;  dA[10] = dA[9] * E;
        dA[11] = E8 * E4;  dA[12] = dA[11] * E;
        dA[13] = dA[11] * E2; dA[14] = dA[13] * E; dA[15] = E8 * E8;
    } else {
#pragma unroll
        for (int n = 0; n < 16; n++) dA[n] = __expf(dv * An[n]);
    }
}

__device__ __forceinline__ int chk_pw(const float An[16])
{
    int pw = 1;
#pragma unroll
    for (int n = 1; n < 16; n++)
        pw = pw && (fabsf(An[n] - (float)(n + 1) * An[0]) <= 3e-4f * (float)(n + 1));
    return pw;
}

__device__ __forceinline__ void scan_step(float h[16], float dv, float uv,
                                          const float Bv[16], const float An[16], int pw)
{
    float dA[16]; mk_dA(dv, An, pw, dA);
    const float du = dv * uv;
#pragma unroll
    for (int n = 0; n < 16; n++) h[n] = fmaf(dA[n], h[n], du * Bv[n]);
}

__device__ __forceinline__ float scan_step_y(float h[16], float dv, float uv,
                                             const float Bv[16], const float Cv[16],
                                             const float An[16], int pw, float Dd)
{
    float dA[16]; mk_dA(dv, An, pw, dA);
    const float du = dv * uv;
    float s[16];
#pragma unroll
    for (int n = 0; n < 16; n++) {
        h[n] = fmaf(dA[n], h[n], du * Bv[n]);
        s[n] = h[n] * Cv[n];
    }
#pragma unroll
    for (int n = 0; n < 8; n++) s[n] += s[n + 8];
#pragma unroll
    for (int n = 0; n < 4; n++) s[n] += s[n + 4];
    s[0] += s[2]; s[1] += s[3];
    return s[0] + s[1] + uv * Dd;
}

// ---------------------------------------------------------------------------
// Scan phase 1: per-chunk local scan (h0=0) -> S[b,c,n,d], sumD[b,c,d].
// ---------------------------------------------------------------------------
__launch_bounds__(256)
__global__ void scan_chunk(const float* __restrict__ dlt,
                           const float* __restrict__ xl,
                           const float* __restrict__ xdbl,
                           const void* __restrict__ A_log,
                           float* __restrict__ S,
                           float* __restrict__ sumD,
                           const void* __restrict__ Dp)
{
    const int isbf = sniff_bf(Dp);
    const int t  = threadIdx.x;
    const int dg = blockIdx.x & 7;
    const int c  = (blockIdx.x >> 3) & (NCH - 1);
    const int b  = blockIdx.x >> 9;
    const int d  = dg * 256 + t;

    float An[16], h[16];
#pragma unroll
    for (int n = 0; n < 16; n++) {
        An[n] = -expf(ldF(A_log, d * 16 + n, isbf));
        h[n] = 0.f;
    }
    const int pw = chk_pw(An);
    float sd = 0.f;
    const size_t r0 = (size_t)b * SEQLEN + c * LC;

    float dv0 = dlt[r0 * D_INNER + d];
    float uv0 = xl [r0 * D_INNER + d];
    float Bv0[16]; ld16f(&xdbl[r0 * 96 + 64], Bv0);

    for (int i = 0; i < LC; i += 2) {
        const size_t r1 = r0 + i + 1;
        float dv1 = dlt[r1 * D_INNER + d];
        float uv1 = xl [r1 * D_INNER + d];
        float Bv1[16]; ld16f(&xdbl[r1 * 96 + 64], Bv1);

        scan_step(h, dv0, uv0, Bv0, An, pw);
        sd += dv0;

        const size_t r2 = r0 + ((i + 2 < LC) ? (i + 2) : (i + 1));  // clamp
        dv0 = dlt[r2 * D_INNER + d];
        uv0 = xl [r2 * D_INNER + d];
        ld16f(&xdbl[r2 * 96 + 64], Bv0);

        scan_step(h, dv1, uv1, Bv1, An, pw);
        sd += dv1;
    }

    const size_t base = (((size_t)b * NCH + c) * 16) * D_INNER + d;
#pragma unroll
    for (int n = 0; n < 16; n++) S[base + (size_t)n * D_INNER] = h[n];
    sumD[((size_t)b * NCH + c) * D_INNER + d] = sd;
}

// ---------------------------------------------------------------------------
// Scan phase 2: combine chunk states; S rewritten with chunk-START state H0.
// ---------------------------------------------------------------------------
__launch_bounds__(256)
__global__ void scan_combine(float* __restrict__ S,
                             const float* __restrict__ sumD,
                             const void* __restrict__ A_log,
                             const void* __restrict__ Dp)
{
    const int isbf = sniff_bf(Dp);
    const int g = blockIdx.x * 256 + threadIdx.x;
    const int d = g & (D_INNER - 1);
    const int n = (g >> 11) & 15;
    const int b = g >> 15;
    const float An = -expf(ldF(A_log, d * 16 + n, isbf));

    float hs = 0.f;
    float Sc = S[(((size_t)b * NCH + 0) * 16 + n) * D_INNER + d];
    float sd = sumD[((size_t)b * NCH + 0) * D_INNER + d];
    for (int c = 0; c < NCH; c++) {
        const int cn = (c + 1 < NCH) ? c + 1 : c;
        const float Scn = S[(((size_t)b * NCH + cn) * 16 + n) * D_INNER + d];
        const float sdn = sumD[((size_t)b * NCH + cn) * D_INNER + d];
        S[(((size_t)b * NCH + c) * 16 + n) * D_INNER + d] = hs;
        hs = fmaf(__expf(An * sd), hs, Sc);
        Sc = Scn; sd = sdn;
    }
}

// ---------------------------------------------------------------------------
// Scan phase 3: seeded re-scan; y = sum_n h*C; D-skip + silu(z) gate -> bf16 yg.
// ---------------------------------------------------------------------------
__launch_bounds__(256)
__global__ void scan_apply(const float* __restrict__ dlt,
                           const float* __restrict__ xl,
                           const float* __restrict__ xdbl,
                           const float* __restrict__ xz,
                           const void* __restrict__ A_log,
                           const void* __restrict__ Dp,
                           const float* __restrict__ S,   // holds H0
                           unsigned short* __restrict__ yg)
{
    const int isbf = sniff_bf(Dp);
    const int t  = threadIdx.x;
    const int dg = blockIdx.x & 7;
    const int c  = (blockIdx.x >> 3) & (NCH - 1);
    const int b  = blockIdx.x >> 9;
    const int d  = dg * 256 + t;

    float An[16], h[16];
    const size_t base = (((size_t)b * NCH + c) * 16) * D_INNER + d;
#pragma unroll
    for (int n = 0; n < 16; n++) {
        An[n] = -expf(ldF(A_log, d * 16 + n, isbf));
        h[n] = S[base + (size_t)n * D_INNER];
    }
    const int pw = chk_pw(An);
    const float Dd = ldF(Dp, d, isbf);
    const size_t r0 = (size_t)b * SEQLEN + c * LC;

    float dv0 = dlt[r0 * D_INNER + d];
    float uv0 = xl [r0 * D_INNER + d];
    float zv0 = xz [r0 * (2 * D_INNER) + D_INNER + d];
    float Bv0[16], Cv0[16];
    ld16f(&xdbl[r0 * 96 + 64], Bv0);
    ld16f(&xdbl[r0 * 96 + 80], Cv0);

    for (int i = 0; i < LC; i += 2) {
        const size_t ra = r0 + i + 1;
        float dv1 = dlt[ra * D_INNER + d];
        float uv1 = xl [ra * D_INNER + d];
        float zv1 = xz [ra * (2 * D_INNER) + D_INNER + d];
        float Bv1[16], Cv1[16];
        ld16f(&xdbl[ra * 96 + 64], Bv1);
        ld16f(&xdbl[ra * 96 + 80], Cv1);

        {
            const float yv = scan_step_y(h, dv0, uv0, Bv0, Cv0, An, pw, Dd);
            yg[(r0 + i) * D_INNER + d] = f2bf(yv * (zv0 / (1.f + __expf(-zv0))));
        }

        const size_t rb = r0 + ((i + 2 < LC) ? (i + 2) : (i + 1));  // clamp
        dv0 = dlt[rb * D_INNER + d];
        uv0 = xl [rb * D_INNER + d];
        zv0 = xz [rb * (2 * D_INNER) + D_INNER + d];
        ld16f(&xdbl[rb * 96 + 64], Bv0);
        ld16f(&xdbl[rb * 96 + 80], Cv0);

        {
            const float yv = scan_step_y(h, dv1, uv1, Bv1, Cv1, An, pw, Dd);
            yg[ra * D_INNER + d] = f2bf(yv * (zv1 / (1.f + __expf(-zv1))));
        }
    }
}

// ---------------------------------------------------------------------------
extern "C" void kernel_launch(void* const* d_in, const int* in_sizes, int n_in,
                              void* d_out, int out_size, void* d_ws, size_t ws_size,
                              hipStream_t stream)
{
    const void* hidden     = d_in[0]; // f32
    const void* in_proj_w  = d_in[1];
    const void* conv_w     = d_in[2];
    const void* conv_b     = d_in[3];
    const void* x_proj_w   = d_in[4];
    const void* dt_proj_w  = d_in[5];
    const void* dt_proj_b  = d_in[6];
    const void* A_log      = d_in[7];
    const void* Dp         = d_in[8];
    const void* out_proj_w = d_in[9];

    char* ws = (char*)d_ws;
    float*          xz   = (float*)(ws);                        // [4096,4096]  64 MB
    float*          xl   = (float*)(ws + 67108864ull);          // [4096,2048]  32 MB
    float*          xdbl = (float*)(ws + 100663296ull);         // [4096,96]   1.5 MB
    float*          dlt  = (float*)(ws + 102236160ull);         // [4096,2048]  32 MB (step 4)
    unsigned short* yg   = (unsigned short*)(ws + 135790592ull);// [4096,2048] bf16 16 MB
    unsigned short* opwB = (unsigned short*)(ws + 152567808ull);// out_proj_w bf16 4 MB
    unsigned short* xdt  = (unsigned short*)(ws + 156762112ull);// [4096,64] bf16 512 KB
    unsigned short* dtwB = (unsigned short*)(ws + 157286400ull);// [2048,64] bf16 256 KB
    unsigned short* xpwB = (unsigned short*)(ws + 157548544ull);// [96,2048] bf16 384 KB (hole)
    float*          S    = (float*)(ws + 169345280ull);         // 16 MB
    float*          sumD = (float*)(ws + 186122496ull);         // 1 MB
    int*            dmap = (int*)  (ws + 187171072ull);         // 256 B probe LUT
    // transient occupants of the dlt region (all dead before gemm_dt writes dlt):
    unsigned short* hidB  = (unsigned short*)(ws + 102236160ull);              // 8 MB (dead after gemm1)
    unsigned short* ipwB  = (unsigned short*)(ws + 102236160ull + 8388608ull); // 8 MB (dead after gemm1)
    unsigned short* xlB   = (unsigned short*)(ws + 102236160ull);              // 16 MB (conv -> gemm_xp)
    float*          xpart = (float*)(ws + 102236160ull + 16777216ull);         // 12.6 MB (gemm_xp -> reduce)

    dim3 blk(256);

    // 0) f32 -> bf16 copies for MFMA operands + block-0 MFMA layout probe
    cvt_all<<<dim3(CVT_TOT / (256 * 8)), blk, 0, stream>>>(
        hidden, in_proj_w, out_proj_w, dt_proj_w, x_proj_w,
        hidB, ipwB, opwB, dtwB, xpwB, Dp, dmap);

    // 1) xz = hidden @ in_proj_w^T   [4096,4096]  (bf16 MFMA, 256^2 8-phase)
    hipFuncSetAttribute((const void*)gemm1_8ph,
                        hipFuncAttributeMaxDynamicSharedMemorySize, 131072);
    gemm1_8ph<<<dim3((NTOK / 256) * (2 * D_INNER / 256)), dim3(512), 131072, stream>>>(
        hidB, ipwB, xz, NTOK, 2 * D_INNER, D_MODEL, dmap);

    // 2) xl = silu(causal_conv1d(x) + conv_b)  (+ bf16 xlB; hidB/ipwB dead now)
    conv_silu<<<dim3((NTOK / 4) * (D_INNER / 4) / 256), blk, 0, stream>>>(
        xz, conv_w, conv_b, xl, xlB, Dp);

    // 3) xdbl = xlB @ xpwB^T  via bf16 MFMA split-K  (+ fused bf16 xdt pack)
    gemm_xp<<<dim3(NTOK / 128, XKS), blk, 0, stream>>>(xlB, xpwB, xpart, dmap);
    xproj_reduce<<<dim3(NTOK * XNC / 256), blk, 0, stream>>>(xpart, xdbl, xdt);

    // 4) delta = softplus(dt @ dt_proj_w^T + dt_proj_b)  (single-stage K=64)
    gemm_dt<<<dim3((NTOK / 128) * (D_INNER / 128)), blk, 0, stream>>>(
        xdt, dtwB, dlt, dmap, dt_proj_b, Dp);

    // 5) chunked parallel scan + D-skip + silu(z) gate -> yg (bf16)
    scan_chunk<<<dim3(BATCH * NCH * (D_INNER / 256)), blk, 0, stream>>>(
        dlt, xl, xdbl, A_log, S, sumD, Dp);
    scan_combine<<<dim3(BATCH * 16 * D_INNER / 256), blk, 0, stream>>>(
        S, sumD, A_log, Dp);
    scan_apply<<<dim3(BATCH * NCH * (D_INNER / 256)), blk, 0, stream>>>(
        dlt, xl, xdbl, xz, A_log, Dp, S, yg);

    // 6) out = yg @ out_proj_w^T -> f32 d_out  (2-phase counted pipeline)
    gemm_op_2ph<<<dim3((NTOK / 128) * (D_MODEL / 64)), blk, 0, stream>>>(
        yg, opwB, (float*)d_out, dmap);
}

// Round 11
// 291.449 us; speedup vs baseline: 1.1555x; 1.0001x over previous
//
#include <hip/hip_runtime.h>

#define D_MODEL 1024
#define D_STATE 16
#define D_CONV  4
#define D_INNER 2048
#define DT_RANK 64
#define BATCH   2
#define SEQLEN  2048
#define NTOK    (BATCH * SEQLEN)   // 4096
#define NCH     64                 // scan chunks
#define LC      (SEQLEN / NCH)     // 32 steps per chunk
#define XKS     8                  // x_proj split-K factor
#define XNC     96                 // dt_rank + 2*d_state

// FACTS (r2-r12): inputs f32; d_out read as f32; bf16 internal copies for MFMA;
// async global_load_lds verified (r9); out_proj split-K regressed (r10); ws peak
// <= 187,171,328 B (r11 abort); dt_proj MFMA verified (r12). r13: out_proj BN=64
// + M-major. r14: in_proj 256^2/BK=64 8-phase — win. r15: scan power-chain —
// win. r16: conv 4x4 blocks — win. r17: out_proj 2-phase counted pipeline — win.
// r18 REGRESSED (conv fused into gemm1: spills + barrier skew). r19: gemm_dt
// single-stage + gate __expf — win. r20/r21 REGRESSED (scan n-split: scan is
// LOAD-ISSUE-bound — never add redundant load issues). r22: revert — 312.0.
// r23: x_proj on bf16 MFMA split-K (gemm_xp) — win, 291.5 best.
// r24 (this round): scan B/C loads de-duplicated — all 256 threads/block were
// issuing 8 global loads/step for the SAME 32 floats (token-row B/C). Stage
// the chunk's 32 xdbl rows in LDS once (1 float4/thread), per-step reads are
// same-address LDS broadcasts. Bit-identical values & order.

// ---------- bf16 helpers ----------
__device__ __forceinline__ float bf2f(unsigned short v) {
    union { unsigned int u; float f; } c; c.u = ((unsigned int)v) << 16; return c.f;
}
__device__ __forceinline__ unsigned short f2bf(float f) {
    union { unsigned int u; float f; } c; c.f = f;
    unsigned int r = c.u + 0x7FFF + ((c.u >> 16) & 1);   // RNE
    return (unsigned short)(r >> 16);
}

__device__ __forceinline__ int sniff_bf(const void* Dp) {
    return (((const unsigned int*)Dp)[0] == 0x3F803F80u) ? 1 : 0;
}

__device__ __forceinline__ float ldF(const void* p, size_t idx, int isbf) {
    return isbf ? bf2f(((const unsigned short*)p)[idx]) : ((const float*)p)[idx];
}
__device__ __forceinline__ void ld16f(const float* p, float* o) {
#pragma unroll
    for (int q = 0; q < 4; q++) {
        float4 v = *(const float4*)(p + 4 * q);
        o[4 * q + 0] = v.x; o[4 * q + 1] = v.y; o[4 * q + 2] = v.z; o[4 * q + 3] = v.w;
    }
}

typedef __attribute__((ext_vector_type(8))) __bf16 bf16x8;
typedef __attribute__((ext_vector_type(4))) float  f32x4;

// ---------------------------------------------------------------------------
// MFMA layout probe (r8-verified), block-0 section of cvt_all.
// dmap[lane*4+r] = row | col<<4 in loader coords.
// ---------------------------------------------------------------------------
__device__ void probe_dmap_block(int t, int* __restrict__ dmap)
{
    __shared__ alignas(16) unsigned short PAs[16 * 32];
    __shared__ alignas(16) unsigned short PBs[16 * 32];
    const int q = (t & 63) >> 4, l15 = t & 15;

    if (t < 64)
        for (int idx = t; idx < 512; idx += 64) {
            PAs[idx] = f2bf((float)(idx >> 5));
            PBs[idx] = f2bf(0.03125f);
        }
    __syncthreads();
    f32x4 acc1 = {0.f, 0.f, 0.f, 0.f};
    if (t < 64) {
        bf16x8 a1 = *(const bf16x8*)&PAs[l15 * 32 + q * 8];
        bf16x8 b1 = *(const bf16x8*)&PBs[l15 * 32 + q * 8];
        acc1 = __builtin_amdgcn_mfma_f32_16x16x32_bf16(a1, b1, acc1, 0, 0, 0);
    }
    __syncthreads();
    if (t < 64)
        for (int idx = t; idx < 512; idx += 64) {
            PAs[idx] = f2bf(0.03125f);
            PBs[idx] = f2bf((float)(idx >> 5));
        }
    __syncthreads();
    if (t < 64) {
        bf16x8 a2 = *(const bf16x8*)&PAs[l15 * 32 + q * 8];
        bf16x8 b2 = *(const bf16x8*)&PBs[l15 * 32 + q * 8];
        f32x4 acc2 = {0.f, 0.f, 0.f, 0.f};
        acc2 = __builtin_amdgcn_mfma_f32_16x16x32_bf16(a2, b2, acc2, 0, 0, 0);
#pragma unroll
        for (int r = 0; r < 4; r++) {
            int ma = (int)(acc1[r] + 0.5f);
            int nb = (int)(acc2[r] + 0.5f);
            if (ma < 0 || ma > 15 || nb < 0 || nb > 15) { ma = q * 4 + r; nb = l15; }
            dmap[t * 4 + r] = ma | (nb << 4);
        }
    }
}

// ---------------------------------------------------------------------------
// Fused bf16 conversion for the 5 MFMA operand copies (8 elems/thread)
// + block-0 MFMA layout probe.
// ---------------------------------------------------------------------------
#define CVT_N0 (NTOK * D_MODEL)        // hidden   4,194,304
#define CVT_N1 (2 * D_INNER * D_MODEL) // in_proj  4,194,304
#define CVT_N2 (D_MODEL * D_INNER)     // out_proj 2,097,152
#define CVT_N3 (D_INNER * DT_RANK)     // dt_proj    131,072
#define CVT_N4 (XNC * D_INNER)         // x_proj     196,608
#define CVT_TOT (CVT_N0 + CVT_N1 + CVT_N2 + CVT_N3 + CVT_N4)

__device__ __forceinline__ void cvt8(const void* in, unsigned short* out,
                                     size_t e0, int isbf)
{
    if (isbf) {
        *(uint4*)(out + e0) = *(const uint4*)((const unsigned short*)in + e0);
    } else {
        const float* f = (const float*)in + e0;
        float4 a = *(const float4*)f;
        float4 b = *(const float4*)(f + 4);
        ushort4 o0 = { f2bf(a.x), f2bf(a.y), f2bf(a.z), f2bf(a.w) };
        ushort4 o1 = { f2bf(b.x), f2bf(b.y), f2bf(b.z), f2bf(b.w) };
        *(ushort4*)(out + e0)     = o0;
        *(ushort4*)(out + e0 + 4) = o1;
    }
}

__launch_bounds__(256)
__global__ void cvt_all(const void* __restrict__ hid, const void* __restrict__ ipw,
                        const void* __restrict__ opw, const void* __restrict__ dtw,
                        const void* __restrict__ xpw,
                        unsigned short* __restrict__ hidB, unsigned short* __restrict__ ipwB,
                        unsigned short* __restrict__ opwB, unsigned short* __restrict__ dtwB,
                        unsigned short* __restrict__ xpwB,
                        const void* __restrict__ Dp, int* __restrict__ dmap)
{
    if (blockIdx.x == 0) probe_dmap_block(threadIdx.x, dmap);

    const int isbf = sniff_bf(Dp);
    size_t e = ((size_t)blockIdx.x * 256 + threadIdx.x) * 8;
    if (e < CVT_N0) { cvt8(hid, hidB, e, isbf); return; }
    e -= CVT_N0;
    if (e < CVT_N1) { cvt8(ipw, ipwB, e, isbf); return; }
    e -= CVT_N1;
    if (e < CVT_N2) { cvt8(opw, opwB, e, isbf); return; }
    e -= CVT_N2;
    if (e < CVT_N3) { cvt8(dtw, dtwB, e, isbf); return; }
    e -= CVT_N3;
    if (e < CVT_N4) { cvt8(xpw, xpwB, e, isbf); }
}

// ---------------------------------------------------------------------------
__device__ __forceinline__ void gl2lds16(const void* g, void* l) {
    __builtin_amdgcn_global_load_lds(
        (const __attribute__((address_space(1))) unsigned int*)g,
        (__attribute__((address_space(3))) unsigned int*)l,
        16, 0, 0);
}

// ===========================================================================
// in_proj GEMM: 256x256 tile, BK=64, 8 waves, 8-phase schedule (r14-verified).
// ===========================================================================
__device__ __forceinline__ void stage_half(const unsigned short* __restrict__ G,
                                           int grow0, int K, int k0,
                                           unsigned short* ldsAB, int half, int t)
{
    const int r8  = t >> 3;                 // 0..63: row within 64-row group
    const int c8  = t & 7;                  // physical 16B slot
    const int swz = (c8 ^ (r8 & 7)) << 3;   // logical col in shorts
#pragma unroll
    for (int j = 0; j < 2; j++) {
        const int row = half * 128 + j * 64 + r8;
        gl2lds16(&G[(size_t)(grow0 + row) * K + k0 + swz],
                 &ldsAB[row * 64 + c8 * 8]);
    }
}

__device__ __forceinline__ bf16x8 ldsfrag(const unsigned short* p, int row, int slot) {
    return *(const bf16x8*)&p[row * 64 + ((slot ^ (row & 7)) << 3)];
}

__launch_bounds__(512)
__global__ void gemm1_8ph(const unsigned short* __restrict__ A,
                          const unsigned short* __restrict__ B,
                          float* __restrict__ C,
                          int M, int N, int K,
                          const int* __restrict__ dmap)
{
    extern __shared__ __align__(16) unsigned short lds[];
    unsigned short* A0l = lds;              // buf0 A [256][64]
    unsigned short* B0l = lds + 16384;      // buf0 B
    unsigned short* A1l = lds + 32768;      // buf1 A
    unsigned short* B1l = lds + 49152;      // buf1 B

    const int t    = threadIdx.x;
    const int lane = t & 63;
    const int w    = t >> 6;
    const int wm   = (w >> 2) * 128, wn = (w & 3) * 64;
    const int q    = lane >> 4, l15 = lane & 15;

    const int nbn  = N >> 8;
    const int nwg  = (M >> 8) * nbn;        // 256 here: % 8 == 0 -> bijective
    const int orig = blockIdx.x;
    const int wg   = (orig & 7) * (nwg >> 3) + (orig >> 3);
    const int bm   = wg / nbn, bn = wg % nbn;
    const int m0   = bm << 8, n0 = bn << 8;
    const int NT   = K >> 6;

    int mp[4];
#pragma unroll
    for (int r = 0; r < 4; r++) mp[r] = dmap[lane * 4 + r];

    f32x4 acc[8][4];
#pragma unroll
    for (int i = 0; i < 8; i++)
#pragma unroll
        for (int j = 0; j < 4; j++) acc[i][j] = (f32x4){0.f, 0.f, 0.f, 0.f};

    // ---- prologue: tile0 {B,A}, tile1 {B}; wait oldest 8 (= tile0 complete)
    stage_half(B, n0, K, 0, B0l, 0, t);
    stage_half(B, n0, K, 0, B0l, 1, t);
    stage_half(A, m0, K, 0, A0l, 0, t);
    stage_half(A, m0, K, 0, A0l, 1, t);
    {
        const int k1 = (NT > 1 ? 64 : 0);
        stage_half(B, n0, K, k1, B1l, 0, t);
        stage_half(B, n0, K, k1, B1l, 1, t);
    }
    asm volatile("s_waitcnt vmcnt(4)" ::: "memory");
    __builtin_amdgcn_s_barrier();

#pragma unroll 2
    for (int tt = 0; tt < NT; ++tt) {
        const int p = tt & 1;
        const unsigned short* Ac = p ? A1l : A0l;
        const unsigned short* Bc = p ? B1l : B0l;
        unsigned short* Anx = p ? A0l : A1l;   // tile tt+1 A (other buf)
        unsigned short* Bnx = p ? B1l : B0l;   // tile tt+2 B (same buf, dead after ph1)
        const int kA = (tt + 1 < NT ? tt + 1 : 0) << 6;
        const int kB = (tt + 2 < NT ? tt + 2 : 0) << 6;

        bf16x8 af[4][2], b0r[2][2], b1r[2][2];

        // ---------------- phase 0: quadrant (mh0, nh0)
#pragma unroll
        for (int i = 0; i < 4; i++)
#pragma unroll
            for (int ks = 0; ks < 2; ks++)
                af[i][ks] = ldsfrag(Ac, wm + i * 16 + l15, ks * 4 + q);
#pragma unroll
        for (int j = 0; j < 2; j++)
#pragma unroll
            for (int ks = 0; ks < 2; ks++)
                b0r[j][ks] = ldsfrag(Bc, wn + j * 16 + l15, ks * 4 + q);
        stage_half(A, m0, K, kA, Anx, 0, t);
        asm volatile("" ::: "memory");
        __builtin_amdgcn_s_barrier();
        __builtin_amdgcn_s_setprio(1);
#pragma unroll
        for (int i = 0; i < 4; i++)
#pragma unroll
            for (int j = 0; j < 2; j++)
#pragma unroll
                for (int ks = 0; ks < 2; ks++)
                    acc[i][j] = __builtin_amdgcn_mfma_f32_16x16x32_bf16(
                        af[i][ks], b0r[j][ks], acc[i][j], 0, 0, 0);
        __builtin_amdgcn_s_setprio(0);
        asm volatile("" ::: "memory");
        __builtin_amdgcn_s_barrier();

        // ---------------- phase 1: quadrant (mh0, nh1)
#pragma unroll
        for (int j = 0; j < 2; j++)
#pragma unroll
            for (int ks = 0; ks < 2; ks++)
                b1r[j][ks] = ldsfrag(Bc, wn + 32 + j * 16 + l15, ks * 4 + q);
        stage_half(A, m0, K, kA, Anx, 1, t);
        asm volatile("" ::: "memory");
        __builtin_amdgcn_s_barrier();
        __builtin_amdgcn_s_setprio(1);
#pragma unroll
        for (int i = 0; i < 4; i++)
#pragma unroll
            for (int j = 0; j < 2; j++)
#pragma unroll
                for (int ks = 0; ks < 2; ks++)
                    acc[i][2 + j] = __builtin_amdgcn_mfma_f32_16x16x32_bf16(
                        af[i][ks], b1r[j][ks], acc[i][2 + j], 0, 0, 0);
        __builtin_amdgcn_s_setprio(0);
        asm volatile("" ::: "memory");
        __builtin_amdgcn_s_barrier();

        // ---------------- phase 2: quadrant (mh1, nh1)
#pragma unroll
        for (int i = 0; i < 4; i++)
#pragma unroll
            for (int ks = 0; ks < 2; ks++)
                af[i][ks] = ldsfrag(Ac, wm + 64 + i * 16 + l15, ks * 4 + q);
        stage_half(B, n0, K, kB, Bnx, 0, t);
        asm volatile("" ::: "memory");
        __builtin_amdgcn_s_barrier();
        __builtin_amdgcn_s_setprio(1);
#pragma unroll
        for (int i = 0; i < 4; i++)
#pragma unroll
            for (int j = 0; j < 2; j++)
#pragma unroll
                for (int ks = 0; ks < 2; ks++)
                    acc[4 + i][2 + j] = __builtin_amdgcn_mfma_f32_16x16x32_bf16(
                        af[i][ks], b1r[j][ks], acc[4 + i][2 + j], 0, 0, 0);
        __builtin_amdgcn_s_setprio(0);
        asm volatile("" ::: "memory");
        __builtin_amdgcn_s_barrier();

        // ---------------- phase 3: quadrant (mh1, nh0)
        stage_half(B, n0, K, kB, Bnx, 1, t);
        asm volatile("" ::: "memory");
        __builtin_amdgcn_s_barrier();
        __builtin_amdgcn_s_setprio(1);
#pragma unroll
        for (int i = 0; i < 4; i++)
#pragma unroll
            for (int j = 0; j < 2; j++)
#pragma unroll
                for (int ks = 0; ks < 2; ks++)
                    acc[4 + i][j] = __builtin_amdgcn_mfma_f32_16x16x32_bf16(
                        af[i][ks], b0r[j][ks], acc[4 + i][j], 0, 0, 0);
        __builtin_amdgcn_s_setprio(0);
        asm volatile("s_waitcnt vmcnt(4)" ::: "memory");
        __builtin_amdgcn_s_barrier();
    }

    // ---- epilogue
#pragma unroll
    for (int i = 0; i < 8; i++) {
#pragma unroll
        for (int r = 0; r < 4; r++) {
            const int mo = mp[r] & 15, no = mp[r] >> 4;
            const int m = m0 + wm + i * 16 + mo;
#pragma unroll
            for (int j = 0; j < 4; j++) {
                const int n = n0 + wn + j * 16 + no;
                C[(size_t)m * N + n] = acc[i][j][r];
            }
        }
    }
}

// ===========================================================================
// out_proj GEMM: 128x64 tile, BK=64, 4 waves, 2-phase counted pipeline
// (r17-verified). T2 XOR-swizzle. Grid 512 = 2 blocks/CU.
// ===========================================================================
__device__ __forceinline__ void stage_op(const unsigned short* __restrict__ A,
                                         const unsigned short* __restrict__ B,
                                         int m0, int n0, int K, int k0,
                                         unsigned short* Al, unsigned short* Bl, int t)
{
    const int r   = t >> 3;                 // 0..31
    const int c8  = t & 7;                  // physical 16B slot
    const int swz = (c8 ^ (r & 7)) << 3;    // logical col in shorts
#pragma unroll
    for (int j = 0; j < 4; j++) {           // A rows 0..127
        const int row = j * 32 + r;
        gl2lds16(&A[(size_t)(m0 + row) * K + k0 + swz], &Al[row * 64 + c8 * 8]);
    }
#pragma unroll
    for (int j = 0; j < 2; j++) {           // B rows 0..63
        const int row = j * 32 + r;
        gl2lds16(&B[(size_t)(n0 + row) * K + k0 + swz], &Bl[row * 64 + c8 * 8]);
    }
}

__launch_bounds__(256)
__global__ void gemm_op_2ph(const unsigned short* __restrict__ A,   // yg [4096][2048]
                            const unsigned short* __restrict__ B,   // opwB [1024][2048]
                            float* __restrict__ C,                  // [4096][1024]
                            const int* __restrict__ dmap)
{
    constexpr int M = NTOK, N = D_MODEL, K = D_INNER;
    constexpr int NT = K / 64;               // 32
    __shared__ alignas(16) unsigned short Al[2][128 * 64];  // 32 KB
    __shared__ alignas(16) unsigned short Bl[2][64 * 64];   // 16 KB

    const int t    = threadIdx.x;
    const int lane = t & 63;
    const int w    = t >> 6;
    const int wm   = (w >> 1) * 64, wn = (w & 1) * 32;
    const int q    = lane >> 4, l15 = lane & 15;

    const int nbn  = N / 64;                 // 16
    const int nwg  = (M / 128) * nbn;        // 512, % 8 == 0
    const int orig = blockIdx.x;
    const int wg   = (orig & 7) * (nwg >> 3) + (orig >> 3);
    const int bm   = wg / nbn, bn = wg % nbn;
    const int m0   = bm * 128, n0 = bn * 64;

    int mp[4];
#pragma unroll
    for (int r = 0; r < 4; r++) mp[r] = dmap[lane * 4 + r];

    f32x4 acc[4][2];
#pragma unroll
    for (int i = 0; i < 4; i++)
#pragma unroll
        for (int j = 0; j < 2; j++) acc[i][j] = (f32x4){0.f, 0.f, 0.f, 0.f};

    stage_op(A, B, m0, n0, K, 0, Al[0], Bl[0], t);
    asm volatile("s_waitcnt vmcnt(0)" ::: "memory");
    __builtin_amdgcn_s_barrier();

#pragma unroll 2
    for (int tt = 0; tt < NT - 1; ++tt) {
        const int cur = tt & 1;
        stage_op(A, B, m0, n0, K, (tt + 1) * 64, Al[cur ^ 1], Bl[cur ^ 1], t);

        bf16x8 af[4][2], bfr[2][2];
#pragma unroll
        for (int i = 0; i < 4; i++)
#pragma unroll
            for (int ks = 0; ks < 2; ks++)
                af[i][ks] = ldsfrag(Al[cur], wm + i * 16 + l15, ks * 4 + q);
#pragma unroll
        for (int j = 0; j < 2; j++)
#pragma unroll
            for (int ks = 0; ks < 2; ks++)
                bfr[j][ks] = ldsfrag(Bl[cur], wn + j * 16 + l15, ks * 4 + q);
        __builtin_amdgcn_s_setprio(1);
#pragma unroll
        for (int i = 0; i < 4; i++)
#pragma unroll
            for (int j = 0; j < 2; j++)
#pragma unroll
                for (int ks = 0; ks < 2; ks++)
                    acc[i][j] = __builtin_amdgcn_mfma_f32_16x16x32_bf16(
                        af[i][ks], bfr[j][ks], acc[i][j], 0, 0, 0);
        __builtin_amdgcn_s_setprio(0);
        asm volatile("s_waitcnt vmcnt(0)" ::: "memory");
        __builtin_amdgcn_s_barrier();
    }

    {
        const int cur = (NT - 1) & 1;
        bf16x8 af[4][2], bfr[2][2];
#pragma unroll
        for (int i = 0; i < 4; i++)
#pragma unroll
            for (int ks = 0; ks < 2; ks++)
                af[i][ks] = ldsfrag(Al[cur], wm + i * 16 + l15, ks * 4 + q);
#pragma unroll
        for (int j = 0; j < 2; j++)
#pragma unroll
            for (int ks = 0; ks < 2; ks++)
                bfr[j][ks] = ldsfrag(Bl[cur], wn + j * 16 + l15, ks * 4 + q);
#pragma unroll
        for (int i = 0; i < 4; i++)
#pragma unroll
            for (int j = 0; j < 2; j++)
#pragma unroll
                for (int ks = 0; ks < 2; ks++)
                    acc[i][j] = __builtin_amdgcn_mfma_f32_16x16x32_bf16(
                        af[i][ks], bfr[j][ks], acc[i][j], 0, 0, 0);
    }

#pragma unroll
    for (int i = 0; i < 4; i++) {
#pragma unroll
        for (int r = 0; r < 4; r++) {
            const int mo = mp[r] & 15, no = mp[r] >> 4;
            const int m = m0 + wm + i * 16 + mo;
#pragma unroll
            for (int j = 0; j < 2; j++) {
                const int n = n0 + wn + j * 16 + no;
                C[(size_t)m * N + n] = acc[i][j][r];
            }
        }
    }
}

// ===========================================================================
// x_proj GEMM (r23-verified): part[z] = xlB[:, z*256:+256] @ xpwB[:, same]^T
// BM=128 x BN=96 (6 n-frags), BK=64, 2-phase counted pipeline, grid 32x8.
// ===========================================================================
__launch_bounds__(256)
__global__ void gemm_xp(const unsigned short* __restrict__ A,   // xlB [4096][2048]
                        const unsigned short* __restrict__ B,   // xpwB [96][2048]
                        float* __restrict__ part,               // [XKS][4096][96]
                        const int* __restrict__ dmap)
{
    constexpr int K  = D_INNER;          // 2048
    constexpr int KC = K / XKS;          // 256 per split-K chunk
    constexpr int NT = KC / 64;          // 4
    __shared__ alignas(16) unsigned short Al[2][128 * 64];  // 32 KB
    __shared__ alignas(16) unsigned short Bl[2][96 * 64];   // 24 KB

    const int t    = threadIdx.x;
    const int lane = t & 63;
    const int w    = t >> 6;
    const int wm   = (w >> 1) * 64, wn = (w & 1) * 48;   // 2x2 waves: 64m x 48n
    const int q    = lane >> 4, l15 = lane & 15;

    const int m0   = blockIdx.x * 128;   // 0..31
    const int z    = blockIdx.y;         // 0..7
    const int koff = z * KC;

    int mp[4];
#pragma unroll
    for (int r = 0; r < 4; r++) mp[r] = dmap[lane * 4 + r];

    f32x4 acc[4][3];
#pragma unroll
    for (int i = 0; i < 4; i++)
#pragma unroll
        for (int j = 0; j < 3; j++) acc[i][j] = (f32x4){0.f, 0.f, 0.f, 0.f};

    auto stage_xp = [&](int k0, unsigned short* Ald, unsigned short* Bld) {
        const int r   = t >> 3;
        const int c8  = t & 7;
        const int swz = (c8 ^ (r & 7)) << 3;
#pragma unroll
        for (int j = 0; j < 4; j++) {        // A rows 0..127
            const int row = j * 32 + r;
            gl2lds16(&A[(size_t)(m0 + row) * K + koff + k0 + swz],
                     &Ald[row * 64 + c8 * 8]);
        }
#pragma unroll
        for (int j = 0; j < 3; j++) {        // B rows 0..95
            const int row = j * 32 + r;
            gl2lds16(&B[(size_t)row * K + koff + k0 + swz],
                     &Bld[row * 64 + c8 * 8]);
        }
    };

    stage_xp(0, Al[0], Bl[0]);
    asm volatile("s_waitcnt vmcnt(0)" ::: "memory");
    __builtin_amdgcn_s_barrier();

#pragma unroll
    for (int tt = 0; tt < NT - 1; ++tt) {
        const int cur = tt & 1;
        stage_xp((tt + 1) * 64, Al[cur ^ 1], Bl[cur ^ 1]);

        bf16x8 af[4][2], bfr[3][2];
#pragma unroll
        for (int i = 0; i < 4; i++)
#pragma unroll
            for (int ks = 0; ks < 2; ks++)
                af[i][ks] = ldsfrag(Al[cur], wm + i * 16 + l15, ks * 4 + q);
#pragma unroll
        for (int j = 0; j < 3; j++)
#pragma unroll
            for (int ks = 0; ks < 2; ks++)
                bfr[j][ks] = ldsfrag(Bl[cur], wn + j * 16 + l15, ks * 4 + q);
        __builtin_amdgcn_s_setprio(1);
#pragma unroll
        for (int i = 0; i < 4; i++)
#pragma unroll
            for (int j = 0; j < 3; j++)
#pragma unroll
                for (int ks = 0; ks < 2; ks++)
                    acc[i][j] = __builtin_amdgcn_mfma_f32_16x16x32_bf16(
                        af[i][ks], bfr[j][ks], acc[i][j], 0, 0, 0);
        __builtin_amdgcn_s_setprio(0);
        asm volatile("s_waitcnt vmcnt(0)" ::: "memory");
        __builtin_amdgcn_s_barrier();
    }

    {
        const int cur = (NT - 1) & 1;
        bf16x8 af[4][2], bfr[3][2];
#pragma unroll
        for (int i = 0; i < 4; i++)
#pragma unroll
            for (int ks = 0; ks < 2; ks++)
                af[i][ks] = ldsfrag(Al[cur], wm + i * 16 + l15, ks * 4 + q);
#pragma unroll
        for (int j = 0; j < 3; j++)
#pragma unroll
            for (int ks = 0; ks < 2; ks++)
                bfr[j][ks] = ldsfrag(Bl[cur], wn + j * 16 + l15, ks * 4 + q);
#pragma unroll
        for (int i = 0; i < 4; i++)
#pragma unroll
            for (int j = 0; j < 3; j++)
#pragma unroll
                for (int ks = 0; ks < 2; ks++)
                    acc[i][j] = __builtin_amdgcn_mfma_f32_16x16x32_bf16(
                        af[i][ks], bfr[j][ks], acc[i][j], 0, 0, 0);
    }

    float* out = part + (size_t)z * NTOK * XNC;
#pragma unroll
    for (int i = 0; i < 4; i++) {
#pragma unroll
        for (int r = 0; r < 4; r++) {
            const int mo = mp[r] & 15, no = mp[r] >> 4;
            const int m = m0 + wm + i * 16 + mo;
#pragma unroll
            for (int j = 0; j < 3; j++) {
                const int n = wn + j * 16 + no;   // < 96 always
                out[(size_t)m * XNC + n] = acc[i][j][r];
            }
        }
    }
}

// ===========================================================================
// dt_proj GEMM (K=64): 128x128 tile, single 32KB stage (r19-verified).
// ===========================================================================
__launch_bounds__(256)
__global__ void gemm_dt(const unsigned short* __restrict__ A,   // xdt [4096][64]
                        const unsigned short* __restrict__ B,   // dtwB [2048][64]
                        float* __restrict__ C,                  // dlt [4096][2048]
                        const int* __restrict__ dmap,
                        const void* __restrict__ bias,
                        const void* __restrict__ Dp)
{
    constexpr int M = NTOK, N = D_INNER, K = DT_RANK;   // 4096, 2048, 64
    __shared__ alignas(16) unsigned short Al[128 * 64]; // 16 KB
    __shared__ alignas(16) unsigned short Bl[128 * 64]; // 16 KB

    const int t    = threadIdx.x;
    const int lane = t & 63;
    const int w    = t >> 6;
    const int wm   = (w >> 1) * 64, wn = (w & 1) * 64;
    const int q    = lane >> 4, l15 = lane & 15;

    const int nbn  = N / 128;                // 16
    const int nwg  = (M / 128) * nbn;        // 512, % 8 == 0 -> bijective
    const int orig = blockIdx.x;
    const int wg   = (orig & 7) * (nwg >> 3) + (orig >> 3);
    const int bm   = wg / nbn, bn = wg % nbn;
    const int m0   = bm * 128, n0 = bn * 128;

    int mp[4];
#pragma unroll
    for (int r = 0; r < 4; r++) mp[r] = dmap[lane * 4 + r];

    {
        const int r   = t >> 3;              // 0..31
        const int c8  = t & 7;
        const int swz = (c8 ^ (r & 7)) << 3;
#pragma unroll
        for (int j = 0; j < 4; j++) {
            const int row = j * 32 + r;
            gl2lds16(&A[(size_t)(m0 + row) * K + swz], &Al[row * 64 + c8 * 8]);
            gl2lds16(&B[(size_t)(n0 + row) * K + swz], &Bl[row * 64 + c8 * 8]);
        }
    }
    asm volatile("s_waitcnt vmcnt(0)" ::: "memory");
    __builtin_amdgcn_s_barrier();

    f32x4 acc[4][4];
#pragma unroll
    for (int i = 0; i < 4; i++)
#pragma unroll
        for (int j = 0; j < 4; j++) acc[i][j] = (f32x4){0.f, 0.f, 0.f, 0.f};

    bf16x8 af[4][2], bfr[4][2];
#pragma unroll
    for (int i = 0; i < 4; i++)
#pragma unroll
        for (int ks = 0; ks < 2; ks++)
            af[i][ks] = ldsfrag(Al, wm + i * 16 + l15, ks * 4 + q);
#pragma unroll
    for (int j = 0; j < 4; j++)
#pragma unroll
        for (int ks = 0; ks < 2; ks++)
            bfr[j][ks] = ldsfrag(Bl, wn + j * 16 + l15, ks * 4 + q);
#pragma unroll
    for (int i = 0; i < 4; i++)
#pragma unroll
        for (int j = 0; j < 4; j++)
#pragma unroll
            for (int ks = 0; ks < 2; ks++)
                acc[i][j] = __builtin_amdgcn_mfma_f32_16x16x32_bf16(
                    af[i][ks], bfr[j][ks], acc[i][j], 0, 0, 0);

    const int isbf = sniff_bf(Dp);
#pragma unroll
    for (int i = 0; i < 4; i++) {
#pragma unroll
        for (int r = 0; r < 4; r++) {
            const int mo = mp[r] & 15, no = mp[r] >> 4;
            const int m = m0 + wm + i * 16 + mo;
#pragma unroll
            for (int j = 0; j < 4; j++) {
                const int n = n0 + wn + j * 16 + no;
                float v = acc[i][j][r] + ldF(bias, n, isbf);
                v = fmaxf(v, 0.f) + __logf(1.f + __expf(-fabsf(v)));   // softplus
                C[(size_t)m * N + n] = v;
            }
        }
    }
}

// reduce split-K parts -> xdbl; also emit bf16 xdt (cols 0..63) for dt-GEMM
__launch_bounds__(256)
__global__ void xproj_reduce(const float* __restrict__ part, float* __restrict__ xdbl,
                             unsigned short* __restrict__ xdt)
{
    const int idx = blockIdx.x * 256 + threadIdx.x;          // NTOK*XNC
    float s = 0.f;
#pragma unroll
    for (int z = 0; z < XKS; z++) s += part[(size_t)z * NTOK * XNC + idx];
    xdbl[idx] = s;
    const int m = idx / XNC;
    const int col = idx - m * XNC;
    if (col < 64) xdt[m * 64 + col] = f2bf(s);
}

// ---------------------------------------------------------------------------
// Depthwise causal conv1d (d_conv=4) + SiLU (r16-verified).
// r23: also emits bf16 xlB for the x_proj MFMA GEMM.
// ---------------------------------------------------------------------------
__launch_bounds__(256)
__global__ void conv_silu(const float* __restrict__ xz,
                          const void* __restrict__ conv_w,
                          const void* __restrict__ conv_b,
                          float* __restrict__ xl,
                          unsigned short* __restrict__ xlB,
                          const void* __restrict__ Dp)
{
    const int isbf = sniff_bf(Dp);
    const int gid = blockIdx.x * 256 + threadIdx.x;   // (NTOK/4)*(D_INNER/4)
    const int dq  = gid & (D_INNER / 4 - 1);          // channel quad 0..511
    const int tg  = gid >> 9;                         // token group 0..1023
    const int d0  = dq * 4;
    const int tok0 = tg * 4;
    const int l0  = tok0 & (SEQLEN - 1);              // position within sequence

    float w[4][4], bias[4];
#pragma unroll
    for (int dd = 0; dd < 4; dd++) {
        bias[dd] = ldF(conv_b, d0 + dd, isbf);
#pragma unroll
        for (int j = 0; j < 4; j++) w[dd][j] = ldF(conv_w, (d0 + dd) * 4 + j, isbf);
    }

    float4 x[7];
    const float* rowp = xz + (size_t)tok0 * (2 * D_INNER) + d0;
#pragma unroll
    for (int k = 0; k < 7; k++) {
        const int off = k - 3;
        if (l0 + off >= 0)
            x[k] = *(const float4*)(rowp + (ptrdiff_t)off * (2 * D_INNER));
        else
            x[k] = (float4){0.f, 0.f, 0.f, 0.f};
    }

#pragma unroll
    for (int tn = 0; tn < 4; tn++) {
        float a0 = bias[0], a1 = bias[1], a2 = bias[2], a3 = bias[3];
#pragma unroll
        for (int j = 0; j < 4; j++) {
            const float4 v = x[tn + j];
            a0 = fmaf(v.x, w[0][j], a0);
            a1 = fmaf(v.y, w[1][j], a1);
            a2 = fmaf(v.z, w[2][j], a2);
            a3 = fmaf(v.w, w[3][j], a3);
        }
        float4 o;
        o.x = a0 / (1.f + __expf(-a0));
        o.y = a1 / (1.f + __expf(-a1));
        o.z = a2 / (1.f + __expf(-a2));
        o.w = a3 / (1.f + __expf(-a3));
        *(float4*)&xl[(size_t)(tok0 + tn) * D_INNER + d0] = o;
        ushort4 ob = { f2bf(o.x), f2bf(o.y), f2bf(o.z), f2bf(o.w) };
        *(ushort4*)&xlB[(size_t)(tok0 + tn) * D_INNER + d0] = ob;
    }
}

// ---------------------------------------------------------------------------
// Scan helpers (r19-verified): dA[n] = exp(dv*An[n]); power chain when
// An[n] ~= (n+1)*An[0] (runtime-verified).
// ---------------------------------------------------------------------------
__device__ __forceinline__ void mk_dA(float dv, const float An[16], int pw, float* dA)
{
    if (pw) {
        const float E = __expf(dv * An[0]);
        dA[0] = E;
        const float E2 = E * E;          dA[1] = E2;
        const float E4 = E2 * E2;        dA[3] = E4;
        const float E8 = E4 * E4;        dA[7] = E8;
        dA[2]  = E2 * E;
        dA[4]  = E4 * E;   dA[5]  = E4 * E2;  dA[6]  = dA[5] * E;
        dA[8]  = E8 * E;   dA[9]  = E8 * E2;  dA[10] = dA[9] * E;
        dA[11] = E8 * E4;  dA[12] = dA[11] * E;
        dA[13] = dA[11] * E2; dA[14] = dA[13] * E; dA[15] = E8 * E8;
    } else {
#pragma unroll
        for (int n = 0; n < 16; n++) dA[n] = __expf(dv * An[n]);
    }
}

__device__ __forceinline__ int chk_pw(const float An[16])
{
    int pw = 1;
#pragma unroll
    for (int n = 1; n < 16; n++)
        pw = pw && (fabsf(An[n] - (float)(n + 1) * An[0]) <= 3e-4f * (float)(n + 1));
    return pw;
}

__device__ __forceinline__ void scan_step(float h[16], float dv, float uv,
                                          const float Bv[16], const float An[16], int pw)
{
    float dA[16]; mk_dA(dv, An, pw, dA);
    const float du = dv * uv;
#pragma unroll
    for (int n = 0; n < 16; n++) h[n] = fmaf(dA[n], h[n], du * Bv[n]);
}

__device__ __forceinline__ float scan_step_y(float h[16], float dv, float uv,
                                             const float Bv[16], const float Cv[16],
                                             const float An[16], int pw, float Dd)
{
    float dA[16]; mk_dA(dv, An, pw, dA);
    const float du = dv * uv;
    float s[16];
#pragma unroll
    for (int n = 0; n < 16; n++) {
        h[n] = fmaf(dA[n], h[n], du * Bv[n]);
        s[n] = h[n] * Cv[n];
    }
#pragma unroll
    for (int n = 0; n < 8; n++) s[n] += s[n + 8];
#pragma unroll
    for (int n = 0; n < 4; n++) s[n] += s[n + 4];
    s[0] += s[2]; s[1] += s[3];
    return s[0] + s[1] + uv * Dd;
}

// ---------------------------------------------------------------------------
// Scan phase 1: per-chunk local scan (h0=0) -> S[b,c,n,d], sumD[b,c,d].
// r24: B rows staged in LDS once per chunk (2 KB); per-step reads are
// same-address LDS broadcasts.
// ---------------------------------------------------------------------------
__launch_bounds__(256)
__global__ void scan_chunk(const float* __restrict__ dlt,
                           const float* __restrict__ xl,
                           const float* __restrict__ xdbl,
                           const void* __restrict__ A_log,
                           float* __restrict__ S,
                           float* __restrict__ sumD,
                           const void* __restrict__ Dp)
{
    __shared__ alignas(16) float xb[LC][16];   // B rows, 2 KB
    const int isbf = sniff_bf(Dp);
    const int t  = threadIdx.x;
    const int dg = blockIdx.x & 7;
    const int c  = (blockIdx.x >> 3) & (NCH - 1);
    const int b  = blockIdx.x >> 9;
    const int d  = dg * 256 + t;
    const size_t r0 = (size_t)b * SEQLEN + c * LC;

    // cooperative stage: 128 threads x 1 float4 = 32 rows x 16 floats
    if (t < LC * 4) {
        const int row = t >> 2, c4 = (t & 3) * 4;
        *(float4*)&xb[row][c4] = *(const float4*)&xdbl[(r0 + row) * 96 + 64 + c4];
    }

    float An[16], h[16];
#pragma unroll
    for (int n = 0; n < 16; n++) {
        An[n] = -expf(ldF(A_log, d * 16 + n, isbf));
        h[n] = 0.f;
    }
    const int pw = chk_pw(An);
    float sd = 0.f;

    float dv0 = dlt[r0 * D_INNER + d];
    float uv0 = xl [r0 * D_INNER + d];
    __syncthreads();

    for (int i = 0; i < LC; i += 2) {
        const size_t r1 = r0 + i + 1;
        float dv1 = dlt[r1 * D_INNER + d];
        float uv1 = xl [r1 * D_INNER + d];

        {
            float Bv[16]; ld16f(&xb[i][0], Bv);
            scan_step(h, dv0, uv0, Bv, An, pw);
            sd += dv0;
        }

        const size_t r2 = r0 + ((i + 2 < LC) ? (i + 2) : (i + 1));  // clamp
        dv0 = dlt[r2 * D_INNER + d];
        uv0 = xl [r2 * D_INNER + d];

        {
            float Bv[16]; ld16f(&xb[i + 1][0], Bv);
            scan_step(h, dv1, uv1, Bv, An, pw);
            sd += dv1;
        }
    }

    const size_t base = (((size_t)b * NCH + c) * 16) * D_INNER + d;
#pragma unroll
    for (int n = 0; n < 16; n++) S[base + (size_t)n * D_INNER] = h[n];
    sumD[((size_t)b * NCH + c) * D_INNER + d] = sd;
}

// ---------------------------------------------------------------------------
// Scan phase 2: combine chunk states; S rewritten with chunk-START state H0.
// ---------------------------------------------------------------------------
__launch_bounds__(256)
__global__ void scan_combine(float* __restrict__ S,
                             const float* __restrict__ sumD,
                             const void* __restrict__ A_log,
                             const void* __restrict__ Dp)
{
    const int isbf = sniff_bf(Dp);
    const int g = blockIdx.x * 256 + threadIdx.x;
    const int d = g & (D_INNER - 1);
    const int n = (g >> 11) & 15;
    const int b = g >> 15;
    const float An = -expf(ldF(A_log, d * 16 + n, isbf));

    float hs = 0.f;
    float Sc = S[(((size_t)b * NCH + 0) * 16 + n) * D_INNER + d];
    float sd = sumD[((size_t)b * NCH + 0) * D_INNER + d];
    for (int c = 0; c < NCH; c++) {
        const int cn = (c + 1 < NCH) ? c + 1 : c;
        const float Scn = S[(((size_t)b * NCH + cn) * 16 + n) * D_INNER + d];
        const float sdn = sumD[((size_t)b * NCH + cn) * D_INNER + d];
        S[(((size_t)b * NCH + c) * 16 + n) * D_INNER + d] = hs;
        hs = fmaf(__expf(An * sd), hs, Sc);
        Sc = Scn; sd = sdn;
    }
}

// ---------------------------------------------------------------------------
// Scan phase 3: seeded re-scan; y = sum_n h*C; D-skip + silu(z) gate -> bf16 yg.
// r24: B+C rows staged in LDS once per chunk (4 KB); per-step reads are
// same-address LDS broadcasts.
// ---------------------------------------------------------------------------
__launch_bounds__(256)
__global__ void scan_apply(const float* __restrict__ dlt,
                           const float* __restrict__ xl,
                           const float* __restrict__ xdbl,
                           const float* __restrict__ xz,
                           const void* __restrict__ A_log,
                           const void* __restrict__ Dp,
                           const float* __restrict__ S,   // holds H0
                           unsigned short* __restrict__ yg)
{
    __shared__ alignas(16) float xbc[LC][32];  // B(0..16)+C(16..32) rows, 4 KB
    const int isbf = sniff_bf(Dp);
    const int t  = threadIdx.x;
    const int dg = blockIdx.x & 7;
    const int c  = (blockIdx.x >> 3) & (NCH - 1);
    const int b  = blockIdx.x >> 9;
    const int d  = dg * 256 + t;
    const size_t r0 = (size_t)b * SEQLEN + c * LC;

    // cooperative stage: 256 threads x 1 float4 = 32 rows x 32 floats
    {
        const int row = t >> 3, c4 = (t & 7) * 4;
        *(float4*)&xbc[row][c4] = *(const float4*)&xdbl[(r0 + row) * 96 + 64 + c4];
    }

    float An[16], h[16];
    const size_t base = (((size_t)b * NCH + c) * 16) * D_INNER + d;
#pragma unroll
    for (int n = 0; n < 16; n++) {
        An[n] = -expf(ldF(A_log, d * 16 + n, isbf));
        h[n] = S[base + (size_t)n * D_INNER];
    }
    const int pw = chk_pw(An);
    const float Dd = ldF(Dp, d, isbf);

    float dv0 = dlt[r0 * D_INNER + d];
    float uv0 = xl [r0 * D_INNER + d];
    float zv0 = xz [r0 * (2 * D_INNER) + D_INNER + d];
    __syncthreads();

    for (int i = 0; i < LC; i += 2) {
        const size_t ra = r0 + i + 1;
        float dv1 = dlt[ra * D_INNER + d];
        float uv1 = xl [ra * D_INNER + d];
        float zv1 = xz [ra * (2 * D_INNER) + D_INNER + d];

        {
            float Bv[16], Cv[16];
            ld16f(&xbc[i][0],  Bv);
            ld16f(&xbc[i][16], Cv);
            const float yv = scan_step_y(h, dv0, uv0, Bv, Cv, An, pw, Dd);
            yg[(r0 + i) * D_INNER + d] = f2bf(yv * (zv0 / (1.f + __expf(-zv0))));
        }

        const size_t rb = r0 + ((i + 2 < LC) ? (i + 2) : (i + 1));  // clamp
        dv0 = dlt[rb * D_INNER + d];
        uv0 = xl [rb * D_INNER + d];
        zv0 = xz [rb * (2 * D_INNER) + D_INNER + d];

        {
            float Bv[16], Cv[16];
            ld16f(&xbc[i + 1][0],  Bv);
            ld16f(&xbc[i + 1][16], Cv);
            const float yv = scan_step_y(h, dv1, uv1, Bv, Cv, An, pw, Dd);
            yg[ra * D_INNER + d] = f2bf(yv * (zv1 / (1.f + __expf(-zv1))));
        }
    }
}

// ---------------------------------------------------------------------------
extern "C" void kernel_launch(void* const* d_in, const int* in_sizes, int n_in,
                              void* d_out, int out_size, void* d_ws, size_t ws_size,
                              hipStream_t stream)
{
    const void* hidden     = d_in[0]; // f32
    const void* in_proj_w  = d_in[1];
    const void* conv_w     = d_in[2];
    const void* conv_b     = d_in[3];
    const void* x_proj_w   = d_in[4];
    const void* dt_proj_w  = d_in[5];
    const void* dt_proj_b  = d_in[6];
    const void* A_log      = d_in[7];
    const void* Dp         = d_in[8];
    const void* out_proj_w = d_in[9];

    char* ws = (char*)d_ws;
    float*          xz   = (float*)(ws);                        // [4096,4096]  64 MB
    float*          xl   = (float*)(ws + 67108864ull);          // [4096,2048]  32 MB
    float*          xdbl = (float*)(ws + 100663296ull);         // [4096,96]   1.5 MB
    float*          dlt  = (float*)(ws + 102236160ull);         // [4096,2048]  32 MB (step 4)
    unsigned short* yg   = (unsigned short*)(ws + 135790592ull);// [4096,2048] bf16 16 MB
    unsigned short* opwB = (unsigned short*)(ws + 152567808ull);// out_proj_w bf16 4 MB
    unsigned short* xdt  = (unsigned short*)(ws + 156762112ull);// [4096,64] bf16 512 KB
    unsigned short* dtwB = (unsigned short*)(ws + 157286400ull);// [2048,64] bf16 256 KB
    unsigned short* xpwB = (unsigned short*)(ws + 157548544ull);// [96,2048] bf16 384 KB (hole)
    float*          S    = (float*)(ws + 169345280ull);         // 16 MB
    float*          sumD = (float*)(ws + 186122496ull);         // 1 MB
    int*            dmap = (int*)  (ws + 187171072ull);         // 256 B probe LUT
    // transient occupants of the dlt region (all dead before gemm_dt writes dlt):
    unsigned short* hidB  = (unsigned short*)(ws + 102236160ull);              // 8 MB (dead after gemm1)
    unsigned short* ipwB  = (unsigned short*)(ws + 102236160ull + 8388608ull); // 8 MB (dead after gemm1)
    unsigned short* xlB   = (unsigned short*)(ws + 102236160ull);              // 16 MB (conv -> gemm_xp)
    float*          xpart = (float*)(ws + 102236160ull + 16777216ull);         // 12.6 MB (gemm_xp -> reduce)

    dim3 blk(256);

    // 0) f32 -> bf16 copies for MFMA operands + block-0 MFMA layout probe
    cvt_all<<<dim3(CVT_TOT / (256 * 8)), blk, 0, stream>>>(
        hidden, in_proj_w, out_proj_w, dt_proj_w, x_proj_w,
        hidB, ipwB, opwB, dtwB, xpwB, Dp, dmap);

    // 1) xz = hidden @ in_proj_w^T   [4096,4096]  (bf16 MFMA, 256^2 8-phase)
    hipFuncSetAttribute((const void*)gemm1_8ph,
                        hipFuncAttributeMaxDynamicSharedMemorySize, 131072);
    gemm1_8ph<<<dim3((NTOK / 256) * (2 * D_INNER / 256)), dim3(512), 131072, stream>>>(
        hidB, ipwB, xz, NTOK, 2 * D_INNER, D_MODEL, dmap);

    // 2) xl = silu(causal_conv1d(x) + conv_b)  (+ bf16 xlB; hidB/ipwB dead now)
    conv_silu<<<dim3((NTOK / 4) * (D_INNER / 4) / 256), blk, 0, stream>>>(
        xz, conv_w, conv_b, xl, xlB, Dp);

    // 3) xdbl = xlB @ xpwB^T  via bf16 MFMA split-K  (+ fused bf16 xdt pack)
    gemm_xp<<<dim3(NTOK / 128, XKS), blk, 0, stream>>>(xlB, xpwB, xpart, dmap);
    xproj_reduce<<<dim3(NTOK * XNC / 256), blk, 0, stream>>>(xpart, xdbl, xdt);

    // 4) delta = softplus(dt @ dt_proj_w^T + dt_proj_b)  (single-stage K=64)
    gemm_dt<<<dim3((NTOK / 128) * (D_INNER / 128)), blk, 0, stream>>>(
        xdt, dtwB, dlt, dmap, dt_proj_b, Dp);

    // 5) chunked parallel scan + D-skip + silu(z) gate -> yg (bf16)
    scan_chunk<<<dim3(BATCH * NCH * (D_INNER / 256)), blk, 0, stream>>>(
        dlt, xl, xdbl, A_log, S, sumD, Dp);
    scan_combine<<<dim3(BATCH * 16 * D_INNER / 256), blk, 0, stream>>>(
        S, sumD, A_log, Dp);
    scan_apply<<<dim3(BATCH * NCH * (D_INNER / 256)), blk, 0, stream>>>(
        dlt, xl, xdbl, xz, A_log, Dp, S, yg);

    // 6) out = yg @ out_proj_w^T -> f32 d_out  (2-phase counted pipeline)
    gemm_op_2ph<<<dim3((NTOK / 128) * (D_MODEL / 64)), blk, 0, stream>>>(
        yg, opwB, (float*)d_out, dmap);
}